// Round 3
// baseline (1371.231 us; speedup 1.0000x reference)
//
#include <hip/hip_runtime.h>

#define NN 50000
#define NE 800000
#define FIN 128
#define H 64
#define NG 64
#define BN_EPS 1e-5f
#define NB_SCAN 196  // ceil(NN/256)

// ---------------- degree histogram (int) ----------------
__global__ void deg_count(const int* __restrict__ dst, int* __restrict__ deg, int E) {
    int e = blockIdx.x * blockDim.x + threadIdx.x;
    if (e < E) atomicAdd(&deg[dst[e]], 1);
}

__global__ void deg_to_dinv(const int* __restrict__ deg, float* __restrict__ dinv, int n) {
    int i = blockIdx.x * blockDim.x + threadIdx.x;
    if (i < n) dinv[i] = rsqrtf((float)deg[i] + 1.0f);
}

// ---------------- prefix sum (exclusive) over deg -> row_start ----------------
__global__ void scan_block(const int* __restrict__ deg, int* __restrict__ row_start,
                           int* __restrict__ aux, int n) {
    __shared__ int s[256];
    int i = blockIdx.x * 256 + threadIdx.x;
    int v = (i < n) ? deg[i] : 0;
    s[threadIdx.x] = v;
    __syncthreads();
    for (int off = 1; off < 256; off <<= 1) {
        int t = (threadIdx.x >= off) ? s[threadIdx.x - off] : 0;
        __syncthreads();
        s[threadIdx.x] += t;
        __syncthreads();
    }
    if (i < n) row_start[i] = s[threadIdx.x] - v;  // exclusive
    if (threadIdx.x == 255) aux[blockIdx.x] = s[255];
}

__global__ void scan_aux(int* __restrict__ aux, int nb) {
    __shared__ int s[256];
    int v = (threadIdx.x < nb) ? aux[threadIdx.x] : 0;
    s[threadIdx.x] = v;
    __syncthreads();
    for (int off = 1; off < 256; off <<= 1) {
        int t = (threadIdx.x >= off) ? s[threadIdx.x - off] : 0;
        __syncthreads();
        s[threadIdx.x] += t;
        __syncthreads();
    }
    if (threadIdx.x < nb) aux[threadIdx.x] = s[threadIdx.x] - v;  // exclusive
}

__global__ void scan_fixup(int* __restrict__ row_start, const int* __restrict__ aux,
                           int* __restrict__ cursor, int n, int E) {
    int i = blockIdx.x * 256 + threadIdx.x;
    if (i < n) {
        int rs = row_start[i] + aux[i >> 8];
        row_start[i] = rs;
        cursor[i] = rs;
    }
    if (i == 0) row_start[n] = E;
}

// ---------------- scatter edges into CSR (by dst), precompute weights ----------------
__global__ void csr_scatter(const int* __restrict__ src, const int* __restrict__ dst,
                            const float* __restrict__ dinv, int* __restrict__ cursor,
                            int* __restrict__ csr_src, float* __restrict__ csr_w, int E) {
    int e = blockIdx.x * blockDim.x + threadIdx.x;
    if (e >= E) return;
    int s = src[e], d = dst[e];
    int j = atomicAdd(&cursor[d], 1);
    csr_src[j] = s;
    csr_w[j] = dinv[s] * dinv[d];
}

// ---------------- register-tiled matmul: out = relu_bn(x) @ W^T ----------------
// Block: 64 rows x 64 cols, 256 threads, thread tile 4x4.
// Xs swizzled by k ^ ((r&7)<<2); Wt swizzled (o,k) -> Wt[k*64 + (o ^ (k&63))].
// Both fill-writes and compute-reads are <=2-way bank aliased (free on CDNA4).
// If stats != nullptr, applies y = relu(x*sc+sh) per input channel while staging
// (fuses the previous layer's BatchNorm+ReLU).
template <int K>
__global__ __launch_bounds__(256, 2) void matmul_fused(const float* __restrict__ x,
                                                       const float* __restrict__ W,
                                                       const float* __restrict__ stats,
                                                       float* __restrict__ out, int n) {
    __shared__ float Xs[64 * K];
    __shared__ float Wt[K * 64];
    const int base = blockIdx.x * 64;

    // stage X (coalesced global read; swizzled conflict-free LDS write)
    for (int i = threadIdx.x; i < 64 * K; i += 256) {
        int r = i / K, k = i % K;
        int row = base + r;
        float v = (row < n) ? x[(size_t)row * K + k] : 0.f;
        if (stats) v = fmaxf(v * stats[128 + k] + stats[192 + k], 0.f);
        Xs[r * K + (k ^ ((r & 7) << 2))] = v;
    }
    // stage W transposed+swizzled (coalesced global read; conflict-free LDS write)
    for (int i = threadIdx.x; i < K * 64; i += 256) {
        int o = i / K, k = i % K;
        Wt[k * 64 + (o ^ (k & 63))] = W[i];
    }
    __syncthreads();

    const int co = (threadIdx.x & 15) * 4;
    const int r0 = (threadIdx.x >> 4) * 4;
    float acc[4][4] = {};

#pragma unroll
    for (int k = 0; k < K; k += 4) {
        float xa[4][4];
#pragma unroll
        for (int i = 0; i < 4; ++i) {
            int r = r0 + i;
            float4 t = *(const float4*)&Xs[r * K + (k ^ ((r & 7) << 2))];
            xa[i][0] = t.x; xa[i][1] = t.y; xa[i][2] = t.z; xa[i][3] = t.w;
        }
        float wv[4][4];
#pragma unroll
        for (int j = 0; j < 4; ++j) {
            int kk = k + j;
            float4 t = *(const float4*)&Wt[kk * 64 + (co ^ (kk & 60))];
            float tt[4] = {t.x, t.y, t.z, t.w};
#pragma unroll
            for (int c = 0; c < 4; ++c) wv[j][c] = tt[c ^ (kk & 3)];
        }
#pragma unroll
        for (int i = 0; i < 4; ++i)
#pragma unroll
            for (int c = 0; c < 4; ++c)
#pragma unroll
                for (int j = 0; j < 4; ++j) acc[i][c] += xa[i][j] * wv[j][c];
    }

    const int row0 = base + r0;
#pragma unroll
    for (int i = 0; i < 4; ++i) {
        if (row0 + i < n) {
            float4 t = make_float4(acc[i][0], acc[i][1], acc[i][2], acc[i][3]);
            *(float4*)&out[(size_t)(row0 + i) * H + co] = t;
        }
    }
}

// ---------------- fused GCN aggregation: gather over CSR + self-loop + bias ----------------
__global__ void gcn_gather(const float* __restrict__ h, const int* __restrict__ row_start,
                           const int* __restrict__ csr_src, const float* __restrict__ csr_w,
                           const float* __restrict__ dinv, const float* __restrict__ bias,
                           float* __restrict__ out, int n) {
    int d = blockIdx.x * 4 + (threadIdx.x >> 6);
    int c = threadIdx.x & 63;
    if (d >= n) return;
    float di = dinv[d];
    float acc = h[(size_t)d * H + c] * di * di + bias[c];
    int j0 = row_start[d], j1 = row_start[d + 1];
    for (int j = j0; j < j1; ++j) {
        int s = csr_src[j];
        float w = csr_w[j];
        acc += h[(size_t)s * H + c] * w;
    }
    out[(size_t)d * H + c] = acc;
}

// ---------------- batchnorm stats ----------------
__global__ void bn_stats(const float* __restrict__ x, float* __restrict__ sum,
                         float* __restrict__ sumsq, int n) {
    int c = threadIdx.x & 63;
    int rg = threadIdx.x >> 6;  // 0..3
    int base = blockIdx.x * 256;
    float s = 0.f, sq = 0.f;
    for (int r = rg; r < 256; r += 4) {
        int row = base + r;
        if (row < n) {
            float v = x[(size_t)row * H + c];
            s += v;
            sq += v * v;
        }
    }
    __shared__ float ls[256], lq[256];
    ls[threadIdx.x] = s;
    lq[threadIdx.x] = sq;
    __syncthreads();
    if (rg == 0) {
        s = ls[c] + ls[c + 64] + ls[c + 128] + ls[c + 192];
        sq = lq[c] + lq[c + 64] + lq[c + 128] + lq[c + 192];
        atomicAdd(&sum[c], s);
        atomicAdd(&sumsq[c], sq);
    }
}

__global__ void bn_finalize(float* __restrict__ stats, const float* __restrict__ g,
                            const float* __restrict__ be, int n) {
    int c = threadIdx.x;
    if (c >= H) return;
    float mean = stats[c] / (float)n;
    float var = stats[64 + c] / (float)n - mean * mean;
    float sc = g[c] * rsqrtf(var + BN_EPS);
    stats[128 + c] = sc;
    stats[192 + c] = be[c] - mean * sc;
}

// ---------------- global mean pool (fuses last BN+ReLU); batch sorted ----------------
#define PROWS 128
__global__ void pool_seg(const float* __restrict__ h, const float* __restrict__ stats,
                         const int* __restrict__ batch, float* __restrict__ pool,
                         float* __restrict__ cnt, int n) {
    int wave = blockIdx.x * 4 + (threadIdx.x >> 6);
    int c = threadIdx.x & 63;
    int r0 = wave * PROWS;
    if (r0 >= n) return;
    int r1 = min(r0 + PROWS, n);
    float sc = stats[128 + c], sh = stats[192 + c];
    int cur = batch[r0];
    float acc = 0.f;
    int nlocal = 0;
    for (int r = r0; r < r1; ++r) {
        int g = batch[r];
        if (g != cur) {
            atomicAdd(&pool[cur * H + c], acc);
            if (c == 0) atomicAdd(&cnt[cur], (float)nlocal);
            cur = g;
            acc = 0.f;
            nlocal = 0;
        }
        acc += fmaxf(h[(size_t)r * H + c] * sc + sh, 0.f);
        ++nlocal;
    }
    atomicAdd(&pool[cur * H + c], acc);
    if (c == 0) atomicAdd(&cnt[cur], (float)nlocal);
}

// ---------------- final MLP: one thread per graph ----------------
__global__ void final_mlp(const float* __restrict__ pool, const float* __restrict__ cnt,
                          const float* __restrict__ l1w, const float* __restrict__ l1b,
                          const float* __restrict__ l2w, const float* __restrict__ l2b,
                          float* __restrict__ out) {
    int g = threadIdx.x;
    if (g >= NG) return;
    float c = fmaxf(cnt[g], 1.0f);
    float inv = 1.0f / c;
    float p[H];
#pragma unroll
    for (int k = 0; k < H; ++k) p[k] = pool[g * H + k] * inv;
    float acc = l2b[0];
    for (int j = 0; j < 32; ++j) {
        float s = l1b[j];
#pragma unroll
        for (int k = 0; k < H; ++k) s += p[k] * l1w[j * H + k];
        acc += fmaxf(s, 0.0f) * l2w[j];
    }
    out[g] = acc;
}

extern "C" void kernel_launch(void* const* d_in, const int* in_sizes, int n_in,
                              void* d_out, int out_size, void* d_ws, size_t ws_size,
                              hipStream_t stream) {
    const float* x = (const float*)d_in[0];
    const int* ei = (const int*)d_in[1];
    const int* batch = (const int*)d_in[2];
    const float* W[3] = {(const float*)d_in[3], (const float*)d_in[7], (const float*)d_in[11]};
    const float* b[3] = {(const float*)d_in[4], (const float*)d_in[8], (const float*)d_in[12]};
    const float* g[3] = {(const float*)d_in[5], (const float*)d_in[9], (const float*)d_in[13]};
    const float* be[3] = {(const float*)d_in[6], (const float*)d_in[10], (const float*)d_in[14]};
    const float* l1w = (const float*)d_in[15];
    const float* l1b = (const float*)d_in[16];
    const float* l2w = (const float*)d_in[17];
    const float* l2b = (const float*)d_in[18];
    float* out = (float*)d_out;

    const int* src = ei;
    const int* dst = ei + NE;

    // ---- workspace layout (4-byte units) ----
    char* wsb = (char*)d_ws;
    size_t off = 0;
    auto alloc = [&](size_t elems) {
        void* p = wsb + off;
        off += elems * 4;
        return p;
    };
    float* dinv = (float*)alloc(50048);
    float* bufA = (float*)alloc((size_t)NN * H);
    float* bufB = (float*)alloc((size_t)NN * H);
    float* st[3] = {(float*)alloc(256), (float*)alloc(256), (float*)alloc(256)};
    float* pool = (float*)alloc(NG * H);
    float* cnt = (float*)alloc(64);
    int* deg = (int*)alloc(50048);
    int* row_start = (int*)alloc(50112);  // NN+1
    int* aux = (int*)alloc(256);
    int* cursor = (int*)alloc(50048);
    int* csr_src = (int*)alloc(NE);
    float* csr_w = (float*)alloc(NE);

    // ---- build dinv + CSR (by dst) ----
    hipMemsetAsync(deg, 0, NN * sizeof(int), stream);
    deg_count<<<(NE + 255) / 256, 256, 0, stream>>>(dst, deg, NE);
    deg_to_dinv<<<(NN + 255) / 256, 256, 0, stream>>>(deg, dinv, NN);
    scan_block<<<NB_SCAN, 256, 0, stream>>>(deg, row_start, aux, NN);
    scan_aux<<<1, 256, 0, stream>>>(aux, NB_SCAN);
    scan_fixup<<<NB_SCAN, 256, 0, stream>>>(row_start, aux, cursor, NN, NE);
    csr_scatter<<<(NE + 255) / 256, 256, 0, stream>>>(src, dst, dinv, cursor, csr_src, csr_w, NE);

    const int grid_mm = (NN + 63) / 64;   // 782
    const int grid_rows = (NN + 3) / 4;   // 12500

    // ---- 3 GCN layers (BN+ReLU of layer L fused into layer L+1's matmul / pool) ----
    for (int L = 0; L < 3; ++L) {
        if (L == 0)
            matmul_fused<FIN><<<grid_mm, 256, 0, stream>>>(x, W[0], nullptr, bufA, NN);
        else
            matmul_fused<H><<<grid_mm, 256, 0, stream>>>(bufB, W[L], st[L - 1], bufA, NN);
        gcn_gather<<<grid_rows, 256, 0, stream>>>(bufA, row_start, csr_src, csr_w, dinv, b[L],
                                                  bufB, NN);
        hipMemsetAsync(st[L], 0, 128 * sizeof(float), stream);
        bn_stats<<<196, 256, 0, stream>>>(bufB, st[L], st[L] + 64, NN);
        bn_finalize<<<1, 64, 0, stream>>>(st[L], g[L], be[L], NN);
    }

    // ---- global mean pool (fused BN of layer 2) + MLP head ----
    hipMemsetAsync(pool, 0, (NG * H + NG) * sizeof(float), stream);
    pool_seg<<<(((NN + PROWS - 1) / PROWS) + 3) / 4, 256, 0, stream>>>(bufB, st[2], batch, pool,
                                                                      cnt, NN);
    final_mlp<<<1, 64, 0, stream>>>(pool, cnt, l1w, l1b, l2w, l2b, out);
}

// Round 4
// 1345.664 us; speedup vs baseline: 1.0190x; 1.0190x over previous
//
#include <hip/hip_runtime.h>

#define NN 50000
#define NE 800000
#define FIN 128
#define H 64
#define NG 64
#define BN_EPS 1e-5f
#define NB_SCAN 196  // ceil(NN/256)

// ---------------- degree histogram (int) ----------------
__global__ void deg_count(const int* __restrict__ dst, int* __restrict__ deg, int E) {
    int e = blockIdx.x * blockDim.x + threadIdx.x;
    if (e < E) atomicAdd(&deg[dst[e]], 1);
}

__global__ void deg_to_dinv(const int* __restrict__ deg, float* __restrict__ dinv, int n) {
    int i = blockIdx.x * blockDim.x + threadIdx.x;
    if (i < n) dinv[i] = rsqrtf((float)deg[i] + 1.0f);
}

// ---------------- prefix sum (exclusive) over deg -> row_start ----------------
__global__ void scan_block(const int* __restrict__ deg, int* __restrict__ row_start,
                           int* __restrict__ aux, int n) {
    __shared__ int s[256];
    int i = blockIdx.x * 256 + threadIdx.x;
    int v = (i < n) ? deg[i] : 0;
    s[threadIdx.x] = v;
    __syncthreads();
    for (int off = 1; off < 256; off <<= 1) {
        int t = (threadIdx.x >= off) ? s[threadIdx.x - off] : 0;
        __syncthreads();
        s[threadIdx.x] += t;
        __syncthreads();
    }
    if (i < n) row_start[i] = s[threadIdx.x] - v;  // exclusive
    if (threadIdx.x == 255) aux[blockIdx.x] = s[255];
}

__global__ void scan_aux(int* __restrict__ aux, int nb) {
    __shared__ int s[256];
    int v = (threadIdx.x < nb) ? aux[threadIdx.x] : 0;
    s[threadIdx.x] = v;
    __syncthreads();
    for (int off = 1; off < 256; off <<= 1) {
        int t = (threadIdx.x >= off) ? s[threadIdx.x - off] : 0;
        __syncthreads();
        s[threadIdx.x] += t;
        __syncthreads();
    }
    if (threadIdx.x < nb) aux[threadIdx.x] = s[threadIdx.x] - v;  // exclusive
}

__global__ void scan_fixup(int* __restrict__ row_start, const int* __restrict__ aux,
                           int* __restrict__ cursor, int n, int E) {
    int i = blockIdx.x * 256 + threadIdx.x;
    if (i < n) {
        int rs = row_start[i] + aux[i >> 8];
        row_start[i] = rs;
        cursor[i] = rs;
    }
    if (i == 0) row_start[n] = E;
}

// ---------------- scatter edges into CSR (by dst), precompute weights ----------------
__global__ void csr_scatter(const int* __restrict__ src, const int* __restrict__ dst,
                            const float* __restrict__ dinv, int* __restrict__ cursor,
                            int* __restrict__ csr_src, float* __restrict__ csr_w, int E) {
    int e = blockIdx.x * blockDim.x + threadIdx.x;
    if (e >= E) return;
    int s = src[e], d = dst[e];
    int j = atomicAdd(&cursor[d], 1);
    csr_src[j] = s;
    csr_w[j] = dinv[s] * dinv[d];
}

// ---------------- transpose W once: Wt[k*64 + o] = W[o*K + k] ----------------
template <int K>
__global__ void transpose_w(const float* __restrict__ W, float* __restrict__ Wt) {
    int i = blockIdx.x * 256 + threadIdx.x;
    if (i < K * 64) {
        int k = i >> 6, o = i & 63;
        Wt[i] = W[o * K + k];
    }
}

// ---------------- register-tiled matmul: out = relu_bn(x) @ W^T ----------------
// Block: 64 rows x 64 cols, 256 threads, thread tile 4x4 (float4 scalars only —
// NO indexed private arrays; round-3's xor-swizzle version demoted its arrays to
// scratch: FETCH 867 MB vs 26 MB ideal, ~540 us/dispatch).
// K chunked at 64: Xs[64][68] (pad 4: fill free, compute reads 2-way), Ws linear
// copy of pre-transposed Wt (2-way compute reads). LDS 33.8 KB -> 4 blocks/CU.
// stats!=nullptr fuses previous layer's BN+ReLU into the X staging load.
template <int K>
__global__ __launch_bounds__(256, 4) void matmul_fused(const float* __restrict__ x,
                                                       const float* __restrict__ Wtg,
                                                       const float* __restrict__ stats,
                                                       float* __restrict__ out, int n) {
    __shared__ float Xs[64 * 68];
    __shared__ float Ws[64 * 64];
    const int base = blockIdx.x * 64;
    const int co = (threadIdx.x & 15) * 4;
    const int r0 = (threadIdx.x >> 4) * 4;

    float4 acc0 = make_float4(0.f, 0.f, 0.f, 0.f);
    float4 acc1 = acc0, acc2 = acc0, acc3 = acc0;

    for (int kc = 0; kc < K; kc += 64) {
        if (kc) __syncthreads();
        // stage X chunk (coalesced global; consecutive LDS within row -> conflict-free)
        for (int i = threadIdx.x; i < 64 * 64; i += 256) {
            int r = i >> 6, k = i & 63;
            int row = base + r;
            float v = (row < n) ? x[(size_t)row * K + kc + k] : 0.f;
            if (stats) {
                int kk = kc + k;
                v = fmaxf(v * stats[128 + kk] + stats[192 + kk], 0.f);
            }
            Xs[r * 68 + k] = v;
        }
        // stage W chunk (pure linear copy -> conflict-free)
        for (int i = threadIdx.x; i < 64 * 64; i += 256) Ws[i] = Wtg[kc * 64 + i];
        __syncthreads();

#pragma unroll
        for (int k = 0; k < 64; k += 4) {
            float4 xa0 = *(const float4*)&Xs[(r0 + 0) * 68 + k];
            float4 xa1 = *(const float4*)&Xs[(r0 + 1) * 68 + k];
            float4 xa2 = *(const float4*)&Xs[(r0 + 2) * 68 + k];
            float4 xa3 = *(const float4*)&Xs[(r0 + 3) * 68 + k];
            float4 w0 = *(const float4*)&Ws[(k + 0) * 64 + co];
            float4 w1 = *(const float4*)&Ws[(k + 1) * 64 + co];
            float4 w2 = *(const float4*)&Ws[(k + 2) * 64 + co];
            float4 w3 = *(const float4*)&Ws[(k + 3) * 64 + co];

            acc0.x += xa0.x * w0.x + xa0.y * w1.x + xa0.z * w2.x + xa0.w * w3.x;
            acc0.y += xa0.x * w0.y + xa0.y * w1.y + xa0.z * w2.y + xa0.w * w3.y;
            acc0.z += xa0.x * w0.z + xa0.y * w1.z + xa0.z * w2.z + xa0.w * w3.z;
            acc0.w += xa0.x * w0.w + xa0.y * w1.w + xa0.z * w2.w + xa0.w * w3.w;

            acc1.x += xa1.x * w0.x + xa1.y * w1.x + xa1.z * w2.x + xa1.w * w3.x;
            acc1.y += xa1.x * w0.y + xa1.y * w1.y + xa1.z * w2.y + xa1.w * w3.y;
            acc1.z += xa1.x * w0.z + xa1.y * w1.z + xa1.z * w2.z + xa1.w * w3.z;
            acc1.w += xa1.x * w0.w + xa1.y * w1.w + xa1.z * w2.w + xa1.w * w3.w;

            acc2.x += xa2.x * w0.x + xa2.y * w1.x + xa2.z * w2.x + xa2.w * w3.x;
            acc2.y += xa2.x * w0.y + xa2.y * w1.y + xa2.z * w2.y + xa2.w * w3.y;
            acc2.z += xa2.x * w0.z + xa2.y * w1.z + xa2.z * w2.z + xa2.w * w3.z;
            acc2.w += xa2.x * w0.w + xa2.y * w1.w + xa2.z * w2.w + xa2.w * w3.w;

            acc3.x += xa3.x * w0.x + xa3.y * w1.x + xa3.z * w2.x + xa3.w * w3.x;
            acc3.y += xa3.x * w0.y + xa3.y * w1.y + xa3.z * w2.y + xa3.w * w3.y;
            acc3.z += xa3.x * w0.z + xa3.y * w1.z + xa3.z * w2.z + xa3.w * w3.z;
            acc3.w += xa3.x * w0.w + xa3.y * w1.w + xa3.z * w2.w + xa3.w * w3.w;
        }
    }

    const int row0 = base + r0;
    if (row0 + 0 < n) *(float4*)&out[(size_t)(row0 + 0) * H + co] = acc0;
    if (row0 + 1 < n) *(float4*)&out[(size_t)(row0 + 1) * H + co] = acc1;
    if (row0 + 2 < n) *(float4*)&out[(size_t)(row0 + 2) * H + co] = acc2;
    if (row0 + 3 < n) *(float4*)&out[(size_t)(row0 + 3) * H + co] = acc3;
}

// ---------------- fused GCN aggregation: gather over CSR + self-loop + bias ----------------
__global__ void gcn_gather(const float* __restrict__ h, const int* __restrict__ row_start,
                           const int* __restrict__ csr_src, const float* __restrict__ csr_w,
                           const float* __restrict__ dinv, const float* __restrict__ bias,
                           float* __restrict__ out, int n) {
    int d = blockIdx.x * 4 + (threadIdx.x >> 6);
    int c = threadIdx.x & 63;
    if (d >= n) return;
    float di = dinv[d];
    float acc = h[(size_t)d * H + c] * di * di + bias[c];
    int j0 = row_start[d], j1 = row_start[d + 1];
    for (int j = j0; j < j1; ++j) {
        int s = csr_src[j];
        float w = csr_w[j];
        acc += h[(size_t)s * H + c] * w;
    }
    out[(size_t)d * H + c] = acc;
}

// ---------------- batchnorm stats ----------------
__global__ void bn_stats(const float* __restrict__ x, float* __restrict__ sum,
                         float* __restrict__ sumsq, int n) {
    int c = threadIdx.x & 63;
    int rg = threadIdx.x >> 6;  // 0..3
    int base = blockIdx.x * 256;
    float s = 0.f, sq = 0.f;
    for (int r = rg; r < 256; r += 4) {
        int row = base + r;
        if (row < n) {
            float v = x[(size_t)row * H + c];
            s += v;
            sq += v * v;
        }
    }
    __shared__ float ls[256], lq[256];
    ls[threadIdx.x] = s;
    lq[threadIdx.x] = sq;
    __syncthreads();
    if (rg == 0) {
        s = ls[c] + ls[c + 64] + ls[c + 128] + ls[c + 192];
        sq = lq[c] + lq[c + 64] + lq[c + 128] + lq[c + 192];
        atomicAdd(&sum[c], s);
        atomicAdd(&sumsq[c], sq);
    }
}

__global__ void bn_finalize(float* __restrict__ stats, const float* __restrict__ g,
                            const float* __restrict__ be, int n) {
    int c = threadIdx.x;
    if (c >= H) return;
    float mean = stats[c] / (float)n;
    float var = stats[64 + c] / (float)n - mean * mean;
    float sc = g[c] * rsqrtf(var + BN_EPS);
    stats[128 + c] = sc;
    stats[192 + c] = be[c] - mean * sc;
}

// ---------------- global mean pool (fuses last BN+ReLU); batch sorted ----------------
#define PROWS 128
__global__ void pool_seg(const float* __restrict__ h, const float* __restrict__ stats,
                         const int* __restrict__ batch, float* __restrict__ pool,
                         float* __restrict__ cnt, int n) {
    int wave = blockIdx.x * 4 + (threadIdx.x >> 6);
    int c = threadIdx.x & 63;
    int r0 = wave * PROWS;
    if (r0 >= n) return;
    int r1 = min(r0 + PROWS, n);
    float sc = stats[128 + c], sh = stats[192 + c];
    int cur = batch[r0];
    float acc = 0.f;
    int nlocal = 0;
    for (int r = r0; r < r1; ++r) {
        int g = batch[r];
        if (g != cur) {
            atomicAdd(&pool[cur * H + c], acc);
            if (c == 0) atomicAdd(&cnt[cur], (float)nlocal);
            cur = g;
            acc = 0.f;
            nlocal = 0;
        }
        acc += fmaxf(h[(size_t)r * H + c] * sc + sh, 0.f);
        ++nlocal;
    }
    atomicAdd(&pool[cur * H + c], acc);
    if (c == 0) atomicAdd(&cnt[cur], (float)nlocal);
}

// ---------------- final MLP: one thread per graph ----------------
__global__ void final_mlp(const float* __restrict__ pool, const float* __restrict__ cnt,
                          const float* __restrict__ l1w, const float* __restrict__ l1b,
                          const float* __restrict__ l2w, const float* __restrict__ l2b,
                          float* __restrict__ out) {
    int g = threadIdx.x;
    if (g >= NG) return;
    float c = fmaxf(cnt[g], 1.0f);
    float inv = 1.0f / c;
    float p[H];
#pragma unroll
    for (int k = 0; k < H; ++k) p[k] = pool[g * H + k] * inv;
    float acc = l2b[0];
    for (int j = 0; j < 32; ++j) {
        float s = l1b[j];
#pragma unroll
        for (int k = 0; k < H; ++k) s += p[k] * l1w[j * H + k];
        acc += fmaxf(s, 0.0f) * l2w[j];
    }
    out[g] = acc;
}

extern "C" void kernel_launch(void* const* d_in, const int* in_sizes, int n_in,
                              void* d_out, int out_size, void* d_ws, size_t ws_size,
                              hipStream_t stream) {
    const float* x = (const float*)d_in[0];
    const int* ei = (const int*)d_in[1];
    const int* batch = (const int*)d_in[2];
    const float* W[3] = {(const float*)d_in[3], (const float*)d_in[7], (const float*)d_in[11]};
    const float* b[3] = {(const float*)d_in[4], (const float*)d_in[8], (const float*)d_in[12]};
    const float* g[3] = {(const float*)d_in[5], (const float*)d_in[9], (const float*)d_in[13]};
    const float* be[3] = {(const float*)d_in[6], (const float*)d_in[10], (const float*)d_in[14]};
    const float* l1w = (const float*)d_in[15];
    const float* l1b = (const float*)d_in[16];
    const float* l2w = (const float*)d_in[17];
    const float* l2b = (const float*)d_in[18];
    float* out = (float*)d_out;

    const int* src = ei;
    const int* dst = ei + NE;

    // ---- workspace layout (4-byte units) ----
    char* wsb = (char*)d_ws;
    size_t off = 0;
    auto alloc = [&](size_t elems) {
        void* p = wsb + off;
        off += elems * 4;
        return p;
    };
    float* dinv = (float*)alloc(50048);
    float* bufA = (float*)alloc((size_t)NN * H);
    float* bufB = (float*)alloc((size_t)NN * H);
    float* st[3] = {(float*)alloc(256), (float*)alloc(256), (float*)alloc(256)};
    float* pool = (float*)alloc(NG * H);
    float* cnt = (float*)alloc(64);
    float* Wt[3] = {(float*)alloc(FIN * 64), (float*)alloc(H * 64), (float*)alloc(H * 64)};
    int* deg = (int*)alloc(50048);
    int* row_start = (int*)alloc(50112);  // NN+1
    int* aux = (int*)alloc(256);
    int* cursor = (int*)alloc(50048);
    int* csr_src = (int*)alloc(NE);
    float* csr_w = (float*)alloc(NE);

    // ---- build dinv + CSR (by dst) + transposed weights ----
    hipMemsetAsync(deg, 0, NN * sizeof(int), stream);
    deg_count<<<(NE + 255) / 256, 256, 0, stream>>>(dst, deg, NE);
    deg_to_dinv<<<(NN + 255) / 256, 256, 0, stream>>>(deg, dinv, NN);
    scan_block<<<NB_SCAN, 256, 0, stream>>>(deg, row_start, aux, NN);
    scan_aux<<<1, 256, 0, stream>>>(aux, NB_SCAN);
    scan_fixup<<<NB_SCAN, 256, 0, stream>>>(row_start, aux, cursor, NN, NE);
    csr_scatter<<<(NE + 255) / 256, 256, 0, stream>>>(src, dst, dinv, cursor, csr_src, csr_w, NE);
    transpose_w<FIN><<<(FIN * 64 + 255) / 256, 256, 0, stream>>>(W[0], Wt[0]);
    transpose_w<H><<<(H * 64 + 255) / 256, 256, 0, stream>>>(W[1], Wt[1]);
    transpose_w<H><<<(H * 64 + 255) / 256, 256, 0, stream>>>(W[2], Wt[2]);

    const int grid_mm = (NN + 63) / 64;   // 782
    const int grid_rows = (NN + 3) / 4;   // 12500

    // ---- 3 GCN layers (BN+ReLU of layer L fused into layer L+1's matmul / pool) ----
    for (int L = 0; L < 3; ++L) {
        if (L == 0)
            matmul_fused<FIN><<<grid_mm, 256, 0, stream>>>(x, Wt[0], nullptr, bufA, NN);
        else
            matmul_fused<H><<<grid_mm, 256, 0, stream>>>(bufB, Wt[L], st[L - 1], bufA, NN);
        gcn_gather<<<grid_rows, 256, 0, stream>>>(bufA, row_start, csr_src, csr_w, dinv, b[L],
                                                  bufB, NN);
        hipMemsetAsync(st[L], 0, 128 * sizeof(float), stream);
        bn_stats<<<196, 256, 0, stream>>>(bufB, st[L], st[L] + 64, NN);
        bn_finalize<<<1, 64, 0, stream>>>(st[L], g[L], be[L], NN);
    }

    // ---- global mean pool (fused BN of layer 2) + MLP head ----
    hipMemsetAsync(pool, 0, (NG * H + NG) * sizeof(float), stream);
    pool_seg<<<(((NN + PROWS - 1) / PROWS) + 3) / 4, 256, 0, stream>>>(bufB, st[2], batch, pool,
                                                                      cnt, NN);
    final_mlp<<<1, 64, 0, stream>>>(pool, cnt, l1w, l1b, l2w, l2b, out);
}

// Round 5
// 764.181 us; speedup vs baseline: 1.7944x; 1.7609x over previous
//
#include <hip/hip_runtime.h>

#define NN 50000
#define NE 800000
#define FIN 128
#define H 64
#define NG 64
#define BN_EPS 1e-5f
#define NB_SCAN 196  // ceil(NN/256)

// ---------------- degree histogram (int) ----------------
__global__ void deg_count(const int* __restrict__ dst, int* __restrict__ deg, int E) {
    int e = blockIdx.x * blockDim.x + threadIdx.x;
    if (e < E) atomicAdd(&deg[dst[e]], 1);
}

__global__ void deg_to_dinv(const int* __restrict__ deg, float* __restrict__ dinv, int n) {
    int i = blockIdx.x * blockDim.x + threadIdx.x;
    if (i < n) dinv[i] = rsqrtf((float)deg[i] + 1.0f);
}

// ---------------- prefix sum (exclusive) over deg -> row_start ----------------
__global__ void scan_block(const int* __restrict__ deg, int* __restrict__ row_start,
                           int* __restrict__ aux, int n) {
    __shared__ int s[256];
    int i = blockIdx.x * 256 + threadIdx.x;
    int v = (i < n) ? deg[i] : 0;
    s[threadIdx.x] = v;
    __syncthreads();
    for (int off = 1; off < 256; off <<= 1) {
        int t = (threadIdx.x >= off) ? s[threadIdx.x - off] : 0;
        __syncthreads();
        s[threadIdx.x] += t;
        __syncthreads();
    }
    if (i < n) row_start[i] = s[threadIdx.x] - v;  // exclusive
    if (threadIdx.x == 255) aux[blockIdx.x] = s[255];
}

__global__ void scan_aux(int* __restrict__ aux, int nb) {
    __shared__ int s[256];
    int v = (threadIdx.x < nb) ? aux[threadIdx.x] : 0;
    s[threadIdx.x] = v;
    __syncthreads();
    for (int off = 1; off < 256; off <<= 1) {
        int t = (threadIdx.x >= off) ? s[threadIdx.x - off] : 0;
        __syncthreads();
        s[threadIdx.x] += t;
        __syncthreads();
    }
    if (threadIdx.x < nb) aux[threadIdx.x] = s[threadIdx.x] - v;  // exclusive
}

__global__ void scan_fixup(int* __restrict__ row_start, const int* __restrict__ aux,
                           int* __restrict__ cursor, int n, int E) {
    int i = blockIdx.x * 256 + threadIdx.x;
    if (i < n) {
        int rs = row_start[i] + aux[i >> 8];
        row_start[i] = rs;
        cursor[i] = rs;
    }
    if (i == 0) row_start[n] = E;
}

// ---------------- scatter edges into CSR (by dst), precompute weights ----------------
__global__ void csr_scatter(const int* __restrict__ src, const int* __restrict__ dst,
                            const float* __restrict__ dinv, int* __restrict__ cursor,
                            int* __restrict__ csr_src, float* __restrict__ csr_w, int E) {
    int e = blockIdx.x * blockDim.x + threadIdx.x;
    if (e >= E) return;
    int s = src[e], d = dst[e];
    int j = atomicAdd(&cursor[d], 1);
    csr_src[j] = s;
    csr_w[j] = dinv[s] * dinv[d];
}

// ---------------- transpose W once: Wt[k*64 + o] = W[o*K + k] ----------------
template <int K>
__global__ void transpose_w(const float* __restrict__ W, float* __restrict__ Wt) {
    int i = blockIdx.x * 256 + threadIdx.x;
    if (i < K * 64) {
        int k = i >> 6, o = i & 63;
        Wt[i] = W[o * K + k];
    }
}

// ---------------- minimal-register matmul: out = relu_bn(x) @ W^T ----------------
// R3/R4 register-tiled versions both spilled to scratch (FETCH 493-867 MB vs 26 MB
// ideal). This version keeps per-thread state tiny: lane = output channel o,
// 4 rows per wave, scalar accumulators only.
// LDS: Ws[k*64+o] = linear copy of pre-transposed Wt -> fill conflict-free;
// compute read (lane=o, fixed k) spans 32 banks 2-way -> free.
// stats!=nullptr fuses previous layer's BN+ReLU into the X load.
template <int K>
__global__ __launch_bounds__(256) void matmul_rows(const float* __restrict__ x,
                                                   const float* __restrict__ Wtg,
                                                   const float* __restrict__ stats,
                                                   float* __restrict__ out, int n) {
    __shared__ float Ws[K * 64];
    for (int i = threadIdx.x; i < K * 64; i += 256) Ws[i] = Wtg[i];
    __syncthreads();

    const int o = threadIdx.x & 63;
    const int row0 = blockIdx.x * 16 + (threadIdx.x >> 6) * 4;
    if (row0 >= n) return;
    const float* xr = x + (size_t)row0 * K;

    float acc0 = 0.f, acc1 = 0.f, acc2 = 0.f, acc3 = 0.f;

    for (int k = 0; k < K; k += 4) {
        float4 x0 = *(const float4*)&xr[k];
        float4 x1 = *(const float4*)&xr[K + k];
        float4 x2 = *(const float4*)&xr[2 * K + k];
        float4 x3 = *(const float4*)&xr[3 * K + k];
        if (stats) {
            float4 sc = *(const float4*)&stats[128 + k];
            float4 sh = *(const float4*)&stats[192 + k];
            x0.x = fmaxf(x0.x * sc.x + sh.x, 0.f); x0.y = fmaxf(x0.y * sc.y + sh.y, 0.f);
            x0.z = fmaxf(x0.z * sc.z + sh.z, 0.f); x0.w = fmaxf(x0.w * sc.w + sh.w, 0.f);
            x1.x = fmaxf(x1.x * sc.x + sh.x, 0.f); x1.y = fmaxf(x1.y * sc.y + sh.y, 0.f);
            x1.z = fmaxf(x1.z * sc.z + sh.z, 0.f); x1.w = fmaxf(x1.w * sc.w + sh.w, 0.f);
            x2.x = fmaxf(x2.x * sc.x + sh.x, 0.f); x2.y = fmaxf(x2.y * sc.y + sh.y, 0.f);
            x2.z = fmaxf(x2.z * sc.z + sh.z, 0.f); x2.w = fmaxf(x2.w * sc.w + sh.w, 0.f);
            x3.x = fmaxf(x3.x * sc.x + sh.x, 0.f); x3.y = fmaxf(x3.y * sc.y + sh.y, 0.f);
            x3.z = fmaxf(x3.z * sc.z + sh.z, 0.f); x3.w = fmaxf(x3.w * sc.w + sh.w, 0.f);
        }
        float w0 = Ws[(k + 0) * 64 + o];
        float w1 = Ws[(k + 1) * 64 + o];
        float w2 = Ws[(k + 2) * 64 + o];
        float w3 = Ws[(k + 3) * 64 + o];
        acc0 += x0.x * w0 + x0.y * w1 + x0.z * w2 + x0.w * w3;
        acc1 += x1.x * w0 + x1.y * w1 + x1.z * w2 + x1.w * w3;
        acc2 += x2.x * w0 + x2.y * w1 + x2.z * w2 + x2.w * w3;
        acc3 += x3.x * w0 + x3.y * w1 + x3.z * w2 + x3.w * w3;
    }

    out[(size_t)(row0 + 0) * H + o] = acc0;
    if (row0 + 1 < n) out[(size_t)(row0 + 1) * H + o] = acc1;
    if (row0 + 2 < n) out[(size_t)(row0 + 2) * H + o] = acc2;
    if (row0 + 3 < n) out[(size_t)(row0 + 3) * H + o] = acc3;
}

// ---------------- fused GCN aggregation: gather over CSR + self-loop + bias ----------------
__global__ void gcn_gather(const float* __restrict__ h, const int* __restrict__ row_start,
                           const int* __restrict__ csr_src, const float* __restrict__ csr_w,
                           const float* __restrict__ dinv, const float* __restrict__ bias,
                           float* __restrict__ out, int n) {
    int d = blockIdx.x * 4 + (threadIdx.x >> 6);
    int c = threadIdx.x & 63;
    if (d >= n) return;
    float di = dinv[d];
    float acc = h[(size_t)d * H + c] * di * di + bias[c];
    int j0 = row_start[d], j1 = row_start[d + 1];
    for (int j = j0; j < j1; ++j) {
        int s = csr_src[j];
        float w = csr_w[j];
        acc += h[(size_t)s * H + c] * w;
    }
    out[(size_t)d * H + c] = acc;
}

// ---------------- batchnorm stats ----------------
__global__ void bn_stats(const float* __restrict__ x, float* __restrict__ sum,
                         float* __restrict__ sumsq, int n) {
    int c = threadIdx.x & 63;
    int rg = threadIdx.x >> 6;  // 0..3
    int base = blockIdx.x * 256;
    float s = 0.f, sq = 0.f;
    for (int r = rg; r < 256; r += 4) {
        int row = base + r;
        if (row < n) {
            float v = x[(size_t)row * H + c];
            s += v;
            sq += v * v;
        }
    }
    __shared__ float ls[256], lq[256];
    ls[threadIdx.x] = s;
    lq[threadIdx.x] = sq;
    __syncthreads();
    if (rg == 0) {
        s = ls[c] + ls[c + 64] + ls[c + 128] + ls[c + 192];
        sq = lq[c] + lq[c + 64] + lq[c + 128] + lq[c + 192];
        atomicAdd(&sum[c], s);
        atomicAdd(&sumsq[c], sq);
    }
}

__global__ void bn_finalize(float* __restrict__ stats, const float* __restrict__ g,
                            const float* __restrict__ be, int n) {
    int c = threadIdx.x;
    if (c >= H) return;
    float mean = stats[c] / (float)n;
    float var = stats[64 + c] / (float)n - mean * mean;
    float sc = g[c] * rsqrtf(var + BN_EPS);
    stats[128 + c] = sc;
    stats[192 + c] = be[c] - mean * sc;
}

// ---------------- global mean pool (fuses last BN+ReLU); batch sorted ----------------
#define PROWS 128
__global__ void pool_seg(const float* __restrict__ h, const float* __restrict__ stats,
                         const int* __restrict__ batch, float* __restrict__ pool,
                         float* __restrict__ cnt, int n) {
    int wave = blockIdx.x * 4 + (threadIdx.x >> 6);
    int c = threadIdx.x & 63;
    int r0 = wave * PROWS;
    if (r0 >= n) return;
    int r1 = min(r0 + PROWS, n);
    float sc = stats[128 + c], sh = stats[192 + c];
    int cur = batch[r0];
    float acc = 0.f;
    int nlocal = 0;
    for (int r = r0; r < r1; ++r) {
        int g = batch[r];
        if (g != cur) {
            atomicAdd(&pool[cur * H + c], acc);
            if (c == 0) atomicAdd(&cnt[cur], (float)nlocal);
            cur = g;
            acc = 0.f;
            nlocal = 0;
        }
        acc += fmaxf(h[(size_t)r * H + c] * sc + sh, 0.f);
        ++nlocal;
    }
    atomicAdd(&pool[cur * H + c], acc);
    if (c == 0) atomicAdd(&cnt[cur], (float)nlocal);
}

// ---------------- final MLP: one thread per graph ----------------
__global__ void final_mlp(const float* __restrict__ pool, const float* __restrict__ cnt,
                          const float* __restrict__ l1w, const float* __restrict__ l1b,
                          const float* __restrict__ l2w, const float* __restrict__ l2b,
                          float* __restrict__ out) {
    int g = threadIdx.x;
    if (g >= NG) return;
    float c = fmaxf(cnt[g], 1.0f);
    float inv = 1.0f / c;
    float p[H];
#pragma unroll
    for (int k = 0; k < H; ++k) p[k] = pool[g * H + k] * inv;
    float acc = l2b[0];
    for (int j = 0; j < 32; ++j) {
        float s = l1b[j];
#pragma unroll
        for (int k = 0; k < H; ++k) s += p[k] * l1w[j * H + k];
        acc += fmaxf(s, 0.0f) * l2w[j];
    }
    out[g] = acc;
}

extern "C" void kernel_launch(void* const* d_in, const int* in_sizes, int n_in,
                              void* d_out, int out_size, void* d_ws, size_t ws_size,
                              hipStream_t stream) {
    const float* x = (const float*)d_in[0];
    const int* ei = (const int*)d_in[1];
    const int* batch = (const int*)d_in[2];
    const float* W[3] = {(const float*)d_in[3], (const float*)d_in[7], (const float*)d_in[11]};
    const float* b[3] = {(const float*)d_in[4], (const float*)d_in[8], (const float*)d_in[12]};
    const float* g[3] = {(const float*)d_in[5], (const float*)d_in[9], (const float*)d_in[13]};
    const float* be[3] = {(const float*)d_in[6], (const float*)d_in[10], (const float*)d_in[14]};
    const float* l1w = (const float*)d_in[15];
    const float* l1b = (const float*)d_in[16];
    const float* l2w = (const float*)d_in[17];
    const float* l2b = (const float*)d_in[18];
    float* out = (float*)d_out;

    const int* src = ei;
    const int* dst = ei + NE;

    // ---- workspace layout (4-byte units) ----
    char* wsb = (char*)d_ws;
    size_t off = 0;
    auto alloc = [&](size_t elems) {
        void* p = wsb + off;
        off += elems * 4;
        return p;
    };
    float* dinv = (float*)alloc(50048);
    float* bufA = (float*)alloc((size_t)NN * H);
    float* bufB = (float*)alloc((size_t)NN * H);
    float* st[3] = {(float*)alloc(256), (float*)alloc(256), (float*)alloc(256)};
    float* pool = (float*)alloc(NG * H);
    float* cnt = (float*)alloc(64);
    float* Wt[3] = {(float*)alloc(FIN * 64), (float*)alloc(H * 64), (float*)alloc(H * 64)};
    int* deg = (int*)alloc(50048);
    int* row_start = (int*)alloc(50112);  // NN+1
    int* aux = (int*)alloc(256);
    int* cursor = (int*)alloc(50048);
    int* csr_src = (int*)alloc(NE);
    float* csr_w = (float*)alloc(NE);

    // ---- build dinv + CSR (by dst) + transposed weights ----
    hipMemsetAsync(deg, 0, NN * sizeof(int), stream);
    deg_count<<<(NE + 255) / 256, 256, 0, stream>>>(dst, deg, NE);
    deg_to_dinv<<<(NN + 255) / 256, 256, 0, stream>>>(deg, dinv, NN);
    scan_block<<<NB_SCAN, 256, 0, stream>>>(deg, row_start, aux, NN);
    scan_aux<<<1, 256, 0, stream>>>(aux, NB_SCAN);
    scan_fixup<<<NB_SCAN, 256, 0, stream>>>(row_start, aux, cursor, NN, NE);
    csr_scatter<<<(NE + 255) / 256, 256, 0, stream>>>(src, dst, dinv, cursor, csr_src, csr_w, NE);
    transpose_w<FIN><<<(FIN * 64 + 255) / 256, 256, 0, stream>>>(W[0], Wt[0]);
    transpose_w<H><<<(H * 64 + 255) / 256, 256, 0, stream>>>(W[1], Wt[1]);
    transpose_w<H><<<(H * 64 + 255) / 256, 256, 0, stream>>>(W[2], Wt[2]);

    const int grid_mm = (NN + 15) / 16;   // 3125
    const int grid_rows = (NN + 3) / 4;   // 12500

    // ---- 3 GCN layers (BN+ReLU of layer L fused into layer L+1's matmul / pool) ----
    for (int L = 0; L < 3; ++L) {
        if (L == 0)
            matmul_rows<FIN><<<grid_mm, 256, 0, stream>>>(x, Wt[0], nullptr, bufA, NN);
        else
            matmul_rows<H><<<grid_mm, 256, 0, stream>>>(bufB, Wt[L], st[L - 1], bufA, NN);
        gcn_gather<<<grid_rows, 256, 0, stream>>>(bufA, row_start, csr_src, csr_w, dinv, b[L],
                                                  bufB, NN);
        hipMemsetAsync(st[L], 0, 128 * sizeof(float), stream);
        bn_stats<<<196, 256, 0, stream>>>(bufB, st[L], st[L] + 64, NN);
        bn_finalize<<<1, 64, 0, stream>>>(st[L], g[L], be[L], NN);
    }

    // ---- global mean pool (fused BN of layer 2) + MLP head ----
    hipMemsetAsync(pool, 0, (NG * H + NG) * sizeof(float), stream);
    pool_seg<<<(((NN + PROWS - 1) / PROWS) + 3) / 4, 256, 0, stream>>>(bufB, st[2], batch, pool,
                                                                      cnt, NN);
    final_mlp<<<1, 64, 0, stream>>>(pool, cnt, l1w, l1b, l2w, l2b, out);
}

// Round 6
// 633.842 us; speedup vs baseline: 2.1634x; 1.2056x over previous
//
#include <hip/hip_runtime.h>

#define NN 50000
#define NE 800000
#define FIN 128
#define H 64
#define NG 64
#define BN_EPS 1e-5f
#define NB_SCAN 196  // ceil(NN/256)

// ---------------- degree histogram (int) ----------------
__global__ void deg_count(const int* __restrict__ dst, int* __restrict__ deg, int E) {
    int e = blockIdx.x * blockDim.x + threadIdx.x;
    if (e < E) atomicAdd(&deg[dst[e]], 1);
}

__global__ void deg_to_dinv(const int* __restrict__ deg, float* __restrict__ dinv, int n) {
    int i = blockIdx.x * blockDim.x + threadIdx.x;
    if (i < n) dinv[i] = rsqrtf((float)deg[i] + 1.0f);
}

// ---------------- prefix sum (exclusive) over deg -> row_start ----------------
__global__ void scan_block(const int* __restrict__ deg, int* __restrict__ row_start,
                           int* __restrict__ aux, int n) {
    __shared__ int s[256];
    int i = blockIdx.x * 256 + threadIdx.x;
    int v = (i < n) ? deg[i] : 0;
    s[threadIdx.x] = v;
    __syncthreads();
    for (int off = 1; off < 256; off <<= 1) {
        int t = (threadIdx.x >= off) ? s[threadIdx.x - off] : 0;
        __syncthreads();
        s[threadIdx.x] += t;
        __syncthreads();
    }
    if (i < n) row_start[i] = s[threadIdx.x] - v;  // exclusive
    if (threadIdx.x == 255) aux[blockIdx.x] = s[255];
}

__global__ void scan_aux(int* __restrict__ aux, int nb) {
    __shared__ int s[256];
    int v = (threadIdx.x < nb) ? aux[threadIdx.x] : 0;
    s[threadIdx.x] = v;
    __syncthreads();
    for (int off = 1; off < 256; off <<= 1) {
        int t = (threadIdx.x >= off) ? s[threadIdx.x - off] : 0;
        __syncthreads();
        s[threadIdx.x] += t;
        __syncthreads();
    }
    if (threadIdx.x < nb) aux[threadIdx.x] = s[threadIdx.x] - v;  // exclusive
}

__global__ void scan_fixup(int* __restrict__ row_start, const int* __restrict__ aux,
                           int* __restrict__ cursor, int n, int E) {
    int i = blockIdx.x * 256 + threadIdx.x;
    if (i < n) {
        int rs = row_start[i] + aux[i >> 8];
        row_start[i] = rs;
        cursor[i] = rs;
    }
    if (i == 0) row_start[n] = E;
}

// ---------------- scatter edges into CSR (by dst), precompute weights ----------------
__global__ void csr_scatter(const int* __restrict__ src, const int* __restrict__ dst,
                            const float* __restrict__ dinv, int* __restrict__ cursor,
                            int* __restrict__ csr_src, float* __restrict__ csr_w, int E) {
    int e = blockIdx.x * blockDim.x + threadIdx.x;
    if (e >= E) return;
    int s = src[e], d = dst[e];
    int j = atomicAdd(&cursor[d], 1);
    csr_src[j] = s;
    csr_w[j] = dinv[s] * dinv[d];
}

// ---------------- transpose W once: Wt[k*64 + o] = W[o*K + k] ----------------
template <int K>
__global__ void transpose_w(const float* __restrict__ W, float* __restrict__ Wt) {
    int i = blockIdx.x * 256 + threadIdx.x;
    if (i < K * 64) {
        int k = i >> 6, o = i & 63;
        Wt[i] = W[o * K + k];
    }
}

// ---------------- minimal-register matmul: out = relu_bn(x) @ W^T ----------------
// (R3/R4 register-tiled versions spilled to scratch: FETCH 493-867 MB vs 26 MB
// ideal. This minimal-register version fixed that — keep it.)
template <int K>
__global__ __launch_bounds__(256) void matmul_rows(const float* __restrict__ x,
                                                   const float* __restrict__ Wtg,
                                                   const float* __restrict__ stats,
                                                   float* __restrict__ out, int n) {
    __shared__ float Ws[K * 64];
    for (int i = threadIdx.x; i < K * 64; i += 256) Ws[i] = Wtg[i];
    __syncthreads();

    const int o = threadIdx.x & 63;
    const int row0 = blockIdx.x * 16 + (threadIdx.x >> 6) * 4;
    if (row0 >= n) return;
    const float* xr = x + (size_t)row0 * K;

    float acc0 = 0.f, acc1 = 0.f, acc2 = 0.f, acc3 = 0.f;

    for (int k = 0; k < K; k += 4) {
        float4 x0 = *(const float4*)&xr[k];
        float4 x1 = *(const float4*)&xr[K + k];
        float4 x2 = *(const float4*)&xr[2 * K + k];
        float4 x3 = *(const float4*)&xr[3 * K + k];
        if (stats) {
            float4 sc = *(const float4*)&stats[128 + k];
            float4 sh = *(const float4*)&stats[192 + k];
            x0.x = fmaxf(x0.x * sc.x + sh.x, 0.f); x0.y = fmaxf(x0.y * sc.y + sh.y, 0.f);
            x0.z = fmaxf(x0.z * sc.z + sh.z, 0.f); x0.w = fmaxf(x0.w * sc.w + sh.w, 0.f);
            x1.x = fmaxf(x1.x * sc.x + sh.x, 0.f); x1.y = fmaxf(x1.y * sc.y + sh.y, 0.f);
            x1.z = fmaxf(x1.z * sc.z + sh.z, 0.f); x1.w = fmaxf(x1.w * sc.w + sh.w, 0.f);
            x2.x = fmaxf(x2.x * sc.x + sh.x, 0.f); x2.y = fmaxf(x2.y * sc.y + sh.y, 0.f);
            x2.z = fmaxf(x2.z * sc.z + sh.z, 0.f); x2.w = fmaxf(x2.w * sc.w + sh.w, 0.f);
            x3.x = fmaxf(x3.x * sc.x + sh.x, 0.f); x3.y = fmaxf(x3.y * sc.y + sh.y, 0.f);
            x3.z = fmaxf(x3.z * sc.z + sh.z, 0.f); x3.w = fmaxf(x3.w * sc.w + sh.w, 0.f);
        }
        float w0 = Ws[(k + 0) * 64 + o];
        float w1 = Ws[(k + 1) * 64 + o];
        float w2 = Ws[(k + 2) * 64 + o];
        float w3 = Ws[(k + 3) * 64 + o];
        acc0 += x0.x * w0 + x0.y * w1 + x0.z * w2 + x0.w * w3;
        acc1 += x1.x * w0 + x1.y * w1 + x1.z * w2 + x1.w * w3;
        acc2 += x2.x * w0 + x2.y * w1 + x2.z * w2 + x2.w * w3;
        acc3 += x3.x * w0 + x3.y * w1 + x3.z * w2 + x3.w * w3;
    }

    out[(size_t)(row0 + 0) * H + o] = acc0;
    if (row0 + 1 < n) out[(size_t)(row0 + 1) * H + o] = acc1;
    if (row0 + 2 < n) out[(size_t)(row0 + 2) * H + o] = acc2;
    if (row0 + 3 < n) out[(size_t)(row0 + 3) * H + o] = acc3;
}

// ---------------- fused GCN aggregation: gather over CSR + self-loop + bias -------------
// R5 version was latency-bound (1 dependent gather chain/wave, 77 us, VALUBusy 15%,
// HBM 16%). Unroll x4 with independent accumulators -> 4 gather chains in flight.
__global__ void gcn_gather(const float* __restrict__ h, const int* __restrict__ row_start,
                           const int* __restrict__ csr_src, const float* __restrict__ csr_w,
                           const float* __restrict__ dinv, const float* __restrict__ bias,
                           float* __restrict__ out, int n) {
    int d = blockIdx.x * 4 + (threadIdx.x >> 6);
    int c = threadIdx.x & 63;
    if (d >= n) return;
    float di = dinv[d];
    float acc0 = h[(size_t)d * H + c] * di * di + bias[c];
    float acc1 = 0.f, acc2 = 0.f, acc3 = 0.f;
    int j0 = row_start[d], j1 = row_start[d + 1];
    int j = j0;
    for (; j + 4 <= j1; j += 4) {
        int s0 = csr_src[j + 0];
        int s1 = csr_src[j + 1];
        int s2 = csr_src[j + 2];
        int s3 = csr_src[j + 3];
        float w0 = csr_w[j + 0];
        float w1 = csr_w[j + 1];
        float w2 = csr_w[j + 2];
        float w3 = csr_w[j + 3];
        float h0 = h[(size_t)s0 * H + c];
        float h1 = h[(size_t)s1 * H + c];
        float h2 = h[(size_t)s2 * H + c];
        float h3 = h[(size_t)s3 * H + c];
        acc0 += h0 * w0;
        acc1 += h1 * w1;
        acc2 += h2 * w2;
        acc3 += h3 * w3;
    }
    for (; j < j1; ++j) acc0 += h[(size_t)csr_src[j] * H + c] * csr_w[j];
    out[(size_t)d * H + c] = (acc0 + acc1) + (acc2 + acc3);
}

// ---------------- batchnorm stats ----------------
__global__ void bn_stats(const float* __restrict__ x, float* __restrict__ sum,
                         float* __restrict__ sumsq, int n) {
    int c = threadIdx.x & 63;
    int rg = threadIdx.x >> 6;  // 0..3
    int base = blockIdx.x * 256;
    float s = 0.f, sq = 0.f;
    for (int r = rg; r < 256; r += 4) {
        int row = base + r;
        if (row < n) {
            float v = x[(size_t)row * H + c];
            s += v;
            sq += v * v;
        }
    }
    __shared__ float ls[256], lq[256];
    ls[threadIdx.x] = s;
    lq[threadIdx.x] = sq;
    __syncthreads();
    if (rg == 0) {
        s = ls[c] + ls[c + 64] + ls[c + 128] + ls[c + 192];
        sq = lq[c] + lq[c + 64] + lq[c + 128] + lq[c + 192];
        atomicAdd(&sum[c], s);
        atomicAdd(&sumsq[c], sq);
    }
}

__global__ void bn_finalize(float* __restrict__ stats, const float* __restrict__ g,
                            const float* __restrict__ be, int n) {
    int c = threadIdx.x;
    if (c >= H) return;
    float mean = stats[c] / (float)n;
    float var = stats[64 + c] / (float)n - mean * mean;
    float sc = g[c] * rsqrtf(var + BN_EPS);
    stats[128 + c] = sc;
    stats[192 + c] = be[c] - mean * sc;
}

// ---------------- global mean pool (fuses last BN+ReLU); batch sorted ----------------
#define PROWS 128
__global__ void pool_seg(const float* __restrict__ h, const float* __restrict__ stats,
                         const int* __restrict__ batch, float* __restrict__ pool,
                         float* __restrict__ cnt, int n) {
    int wave = blockIdx.x * 4 + (threadIdx.x >> 6);
    int c = threadIdx.x & 63;
    int r0 = wave * PROWS;
    if (r0 >= n) return;
    int r1 = min(r0 + PROWS, n);
    float sc = stats[128 + c], sh = stats[192 + c];
    int cur = batch[r0];
    float acc = 0.f;
    int nlocal = 0;
    for (int r = r0; r < r1; ++r) {
        int g = batch[r];
        if (g != cur) {
            atomicAdd(&pool[cur * H + c], acc);
            if (c == 0) atomicAdd(&cnt[cur], (float)nlocal);
            cur = g;
            acc = 0.f;
            nlocal = 0;
        }
        acc += fmaxf(h[(size_t)r * H + c] * sc + sh, 0.f);
        ++nlocal;
    }
    atomicAdd(&pool[cur * H + c], acc);
    if (c == 0) atomicAdd(&cnt[cur], (float)nlocal);
}

// ---------------- final MLP: one thread per graph ----------------
__global__ void final_mlp(const float* __restrict__ pool, const float* __restrict__ cnt,
                          const float* __restrict__ l1w, const float* __restrict__ l1b,
                          const float* __restrict__ l2w, const float* __restrict__ l2b,
                          float* __restrict__ out) {
    int g = threadIdx.x;
    if (g >= NG) return;
    float c = fmaxf(cnt[g], 1.0f);
    float inv = 1.0f / c;
    float p[H];
#pragma unroll
    for (int k = 0; k < H; ++k) p[k] = pool[g * H + k] * inv;
    float acc = l2b[0];
    for (int j = 0; j < 32; ++j) {
        float s = l1b[j];
#pragma unroll
        for (int k = 0; k < H; ++k) s += p[k] * l1w[j * H + k];
        acc += fmaxf(s, 0.0f) * l2w[j];
    }
    out[g] = acc;
}

extern "C" void kernel_launch(void* const* d_in, const int* in_sizes, int n_in,
                              void* d_out, int out_size, void* d_ws, size_t ws_size,
                              hipStream_t stream) {
    const float* x = (const float*)d_in[0];
    const int* ei = (const int*)d_in[1];
    const int* batch = (const int*)d_in[2];
    const float* W[3] = {(const float*)d_in[3], (const float*)d_in[7], (const float*)d_in[11]};
    const float* b[3] = {(const float*)d_in[4], (const float*)d_in[8], (const float*)d_in[12]};
    const float* g[3] = {(const float*)d_in[5], (const float*)d_in[9], (const float*)d_in[13]};
    const float* be[3] = {(const float*)d_in[6], (const float*)d_in[10], (const float*)d_in[14]};
    const float* l1w = (const float*)d_in[15];
    const float* l1b = (const float*)d_in[16];
    const float* l2w = (const float*)d_in[17];
    const float* l2b = (const float*)d_in[18];
    float* out = (float*)d_out;

    const int* src = ei;
    const int* dst = ei + NE;

    // ---- workspace layout (4-byte units) ----
    char* wsb = (char*)d_ws;
    size_t off = 0;
    auto alloc = [&](size_t elems) {
        void* p = wsb + off;
        off += elems * 4;
        return p;
    };
    float* dinv = (float*)alloc(50048);
    float* bufA = (float*)alloc((size_t)NN * H);
    float* bufB = (float*)alloc((size_t)NN * H);
    float* st[3] = {(float*)alloc(256), (float*)alloc(256), (float*)alloc(256)};
    float* pool = (float*)alloc(NG * H);
    float* cnt = (float*)alloc(64);
    float* Wt[3] = {(float*)alloc(FIN * 64), (float*)alloc(H * 64), (float*)alloc(H * 64)};
    int* deg = (int*)alloc(50048);
    int* row_start = (int*)alloc(50112);  // NN+1
    int* aux = (int*)alloc(256);
    int* cursor = (int*)alloc(50048);
    int* csr_src = (int*)alloc(NE);
    float* csr_w = (float*)alloc(NE);

    // ---- build dinv + CSR (by dst) + transposed weights ----
    hipMemsetAsync(deg, 0, NN * sizeof(int), stream);
    deg_count<<<(NE + 255) / 256, 256, 0, stream>>>(dst, deg, NE);
    deg_to_dinv<<<(NN + 255) / 256, 256, 0, stream>>>(deg, dinv, NN);
    scan_block<<<NB_SCAN, 256, 0, stream>>>(deg, row_start, aux, NN);
    scan_aux<<<1, 256, 0, stream>>>(aux, NB_SCAN);
    scan_fixup<<<NB_SCAN, 256, 0, stream>>>(row_start, aux, cursor, NN, NE);
    csr_scatter<<<(NE + 255) / 256, 256, 0, stream>>>(src, dst, dinv, cursor, csr_src, csr_w, NE);
    transpose_w<FIN><<<(FIN * 64 + 255) / 256, 256, 0, stream>>>(W[0], Wt[0]);
    transpose_w<H><<<(H * 64 + 255) / 256, 256, 0, stream>>>(W[1], Wt[1]);
    transpose_w<H><<<(H * 64 + 255) / 256, 256, 0, stream>>>(W[2], Wt[2]);

    const int grid_mm = (NN + 15) / 16;   // 3125
    const int grid_rows = (NN + 3) / 4;   // 12500

    // ---- 3 GCN layers (BN+ReLU of layer L fused into layer L+1's matmul / pool) ----
    for (int L = 0; L < 3; ++L) {
        if (L == 0)
            matmul_rows<FIN><<<grid_mm, 256, 0, stream>>>(x, Wt[0], nullptr, bufA, NN);
        else
            matmul_rows<H><<<grid_mm, 256, 0, stream>>>(bufB, Wt[L], st[L - 1], bufA, NN);
        gcn_gather<<<grid_rows, 256, 0, stream>>>(bufA, row_start, csr_src, csr_w, dinv, b[L],
                                                  bufB, NN);
        hipMemsetAsync(st[L], 0, 128 * sizeof(float), stream);
        bn_stats<<<196, 256, 0, stream>>>(bufB, st[L], st[L] + 64, NN);
        bn_finalize<<<1, 64, 0, stream>>>(st[L], g[L], be[L], NN);
    }

    // ---- global mean pool (fused BN of layer 2) + MLP head ----
    hipMemsetAsync(pool, 0, (NG * H + NG) * sizeof(float), stream);
    pool_seg<<<(((NN + PROWS - 1) / PROWS) + 3) / 4, 256, 0, stream>>>(bufB, st[2], batch, pool,
                                                                      cnt, NN);
    final_mlp<<<1, 64, 0, stream>>>(pool, cnt, l1w, l1b, l2w, l2b, out);
}

// Round 7
// 567.548 us; speedup vs baseline: 2.4161x; 1.1168x over previous
//
#include <hip/hip_runtime.h>

#define NN 50000
#define NE 800000
#define FIN 128
#define H 64
#define NG 64
#define BN_EPS 1e-5f
#define NB_SCAN 196  // ceil(NN/256)

// ---------------- degree histogram (int) ----------------
__global__ void deg_count(const int* __restrict__ dst, int* __restrict__ deg, int E) {
    int e = blockIdx.x * blockDim.x + threadIdx.x;
    if (e < E) atomicAdd(&deg[dst[e]], 1);
}

// also zeroes the BN-stat accumulators and pool/cnt (folds 4 memset launches)
__global__ void deg_to_dinv(const int* __restrict__ deg, float* __restrict__ dinv,
                            float* __restrict__ z0, float* __restrict__ z1,
                            float* __restrict__ z2, float* __restrict__ poolcnt, int n) {
    int i = blockIdx.x * blockDim.x + threadIdx.x;
    if (i < n) dinv[i] = rsqrtf((float)deg[i] + 1.0f);
    if (i < 128) { z0[i] = 0.f; z1[i] = 0.f; z2[i] = 0.f; }
    if (i < NG * H + NG) poolcnt[i] = 0.f;
}

// ---------------- prefix sum (exclusive) over deg -> row_start ----------------
__global__ void scan_block(const int* __restrict__ deg, int* __restrict__ row_start,
                           int* __restrict__ aux, int n) {
    __shared__ int s[256];
    int i = blockIdx.x * 256 + threadIdx.x;
    int v = (i < n) ? deg[i] : 0;
    s[threadIdx.x] = v;
    __syncthreads();
    for (int off = 1; off < 256; off <<= 1) {
        int t = (threadIdx.x >= off) ? s[threadIdx.x - off] : 0;
        __syncthreads();
        s[threadIdx.x] += t;
        __syncthreads();
    }
    if (i < n) row_start[i] = s[threadIdx.x] - v;  // exclusive
    if (threadIdx.x == 255) aux[blockIdx.x] = s[255];
}

__global__ void scan_aux(int* __restrict__ aux, int nb) {
    __shared__ int s[256];
    int v = (threadIdx.x < nb) ? aux[threadIdx.x] : 0;
    s[threadIdx.x] = v;
    __syncthreads();
    for (int off = 1; off < 256; off <<= 1) {
        int t = (threadIdx.x >= off) ? s[threadIdx.x - off] : 0;
        __syncthreads();
        s[threadIdx.x] += t;
        __syncthreads();
    }
    if (threadIdx.x < nb) aux[threadIdx.x] = s[threadIdx.x] - v;  // exclusive
}

__global__ void scan_fixup(int* __restrict__ row_start, const int* __restrict__ aux,
                           int* __restrict__ cursor, int n, int E) {
    int i = blockIdx.x * 256 + threadIdx.x;
    if (i < n) {
        int rs = row_start[i] + aux[i >> 8];
        row_start[i] = rs;
        cursor[i] = rs;
    }
    if (i == 0) row_start[n] = E;
}

// ---------------- scatter edges into CSR (by dst), precompute weights ----------------
__global__ void csr_scatter(const int* __restrict__ src, const int* __restrict__ dst,
                            const float* __restrict__ dinv, int* __restrict__ cursor,
                            int* __restrict__ csr_src, float* __restrict__ csr_w, int E) {
    int e = blockIdx.x * blockDim.x + threadIdx.x;
    if (e >= E) return;
    int s = src[e], d = dst[e];
    int j = atomicAdd(&cursor[d], 1);
    csr_src[j] = s;
    csr_w[j] = dinv[s] * dinv[d];
}

// ---------------- transpose W once: Wt[k*64 + o] = W[o*K + k] ----------------
template <int K>
__global__ void transpose_w(const float* __restrict__ W, float* __restrict__ Wt) {
    int i = blockIdx.x * 256 + threadIdx.x;
    if (i < K * 64) {
        int k = i >> 6, o = i & 63;
        Wt[i] = W[o * K + k];
    }
}

// ---------------- matmul: out = x @ W^T, 8 rows/thread ----------------
// R6 post-mortem: fused-BN 4-row version hit VGPR=188 -> 9.6% occupancy,
// latency-bound at 72 us. This version: no BN fusion (separate cheap pass),
// 8 rows/thread amortizes W LDS reads, launch_bounds(256,4) caps VGPR at 128.
// LDS reads Ws[k*64+o] lane=o -> 2-way bank alias (free). No private arrays
// (R3/R4 scratch-spill lesson).
template <int K>
__global__ __launch_bounds__(256, 4) void matmul_rows8(const float* __restrict__ x,
                                                       const float* __restrict__ Wtg,
                                                       float* __restrict__ out, int n) {
    __shared__ float Ws[K * 64];
    for (int i = threadIdx.x; i < K * 64; i += 256) Ws[i] = Wtg[i];
    __syncthreads();

    const int o = threadIdx.x & 63;
    const int r0 = blockIdx.x * 32 + (threadIdx.x >> 6) * 8;
    if (r0 >= n) return;
    const float* xr = x + (size_t)r0 * K;

    float acc0 = 0.f, acc1 = 0.f, acc2 = 0.f, acc3 = 0.f;
    float acc4 = 0.f, acc5 = 0.f, acc6 = 0.f, acc7 = 0.f;

    if (r0 + 8 <= n) {
#pragma unroll 2
        for (int k = 0; k < K; k += 4) {
            float4 x0 = *(const float4*)&xr[0 * K + k];
            float4 x1 = *(const float4*)&xr[1 * K + k];
            float4 x2 = *(const float4*)&xr[2 * K + k];
            float4 x3 = *(const float4*)&xr[3 * K + k];
            float4 x4 = *(const float4*)&xr[4 * K + k];
            float4 x5 = *(const float4*)&xr[5 * K + k];
            float4 x6 = *(const float4*)&xr[6 * K + k];
            float4 x7 = *(const float4*)&xr[7 * K + k];
            float w0 = Ws[(k + 0) * 64 + o];
            float w1 = Ws[(k + 1) * 64 + o];
            float w2 = Ws[(k + 2) * 64 + o];
            float w3 = Ws[(k + 3) * 64 + o];
            acc0 += x0.x * w0 + x0.y * w1 + x0.z * w2 + x0.w * w3;
            acc1 += x1.x * w0 + x1.y * w1 + x1.z * w2 + x1.w * w3;
            acc2 += x2.x * w0 + x2.y * w1 + x2.z * w2 + x2.w * w3;
            acc3 += x3.x * w0 + x3.y * w1 + x3.z * w2 + x3.w * w3;
            acc4 += x4.x * w0 + x4.y * w1 + x4.z * w2 + x4.w * w3;
            acc5 += x5.x * w0 + x5.y * w1 + x5.z * w2 + x5.w * w3;
            acc6 += x6.x * w0 + x6.y * w1 + x6.z * w2 + x6.w * w3;
            acc7 += x7.x * w0 + x7.y * w1 + x7.z * w2 + x7.w * w3;
        }
        out[(size_t)(r0 + 0) * H + o] = acc0;
        out[(size_t)(r0 + 1) * H + o] = acc1;
        out[(size_t)(r0 + 2) * H + o] = acc2;
        out[(size_t)(r0 + 3) * H + o] = acc3;
        out[(size_t)(r0 + 4) * H + o] = acc4;
        out[(size_t)(r0 + 5) * H + o] = acc5;
        out[(size_t)(r0 + 6) * H + o] = acc6;
        out[(size_t)(r0 + 7) * H + o] = acc7;
    } else {
        for (int i = 0; i < 8; ++i) {
            int row = r0 + i;
            if (row >= n) break;
            float acc = 0.f;
            for (int k = 0; k < K; ++k) acc += x[(size_t)row * K + k] * Ws[k * 64 + o];
            out[(size_t)row * H + o] = acc;
        }
    }
}

// ---------------- BN apply + ReLU (separate cheap float4 pass) ----------------
__global__ void bn_apply4(float* __restrict__ xio, const float* __restrict__ stats, int n4) {
    int idx = blockIdx.x * 256 + threadIdx.x;
    if (idx >= n4) return;
    int cb = (idx & 15) * 4;
    float4 sc = *(const float4*)&stats[128 + cb];
    float4 sh = *(const float4*)&stats[192 + cb];
    float4 v = ((float4*)xio)[idx];
    v.x = fmaxf(v.x * sc.x + sh.x, 0.f);
    v.y = fmaxf(v.y * sc.y + sh.y, 0.f);
    v.z = fmaxf(v.z * sc.z + sh.z, 0.f);
    v.w = fmaxf(v.w * sc.w + sh.w, 0.f);
    ((float4*)xio)[idx] = v;
}

// ---------------- fused GCN aggregation: gather over CSR + self-loop + bias -------------
// 8 independent gather chains in flight per wave (R5 1-chain was latency-bound).
__global__ void gcn_gather(const float* __restrict__ h, const int* __restrict__ row_start,
                           const int* __restrict__ csr_src, const float* __restrict__ csr_w,
                           const float* __restrict__ dinv, const float* __restrict__ bias,
                           float* __restrict__ out, int n) {
    int d = blockIdx.x * 4 + (threadIdx.x >> 6);
    int c = threadIdx.x & 63;
    if (d >= n) return;
    float di = dinv[d];
    float a0 = h[(size_t)d * H + c] * di * di + bias[c];
    float a1 = 0.f, a2 = 0.f, a3 = 0.f, a4 = 0.f, a5 = 0.f, a6 = 0.f, a7 = 0.f;
    int j0 = row_start[d], j1 = row_start[d + 1];
    int j = j0;
    for (; j + 8 <= j1; j += 8) {
        int s0 = csr_src[j + 0], s1 = csr_src[j + 1], s2 = csr_src[j + 2], s3 = csr_src[j + 3];
        int s4 = csr_src[j + 4], s5 = csr_src[j + 5], s6 = csr_src[j + 6], s7 = csr_src[j + 7];
        float w0 = csr_w[j + 0], w1 = csr_w[j + 1], w2 = csr_w[j + 2], w3 = csr_w[j + 3];
        float w4 = csr_w[j + 4], w5 = csr_w[j + 5], w6 = csr_w[j + 6], w7 = csr_w[j + 7];
        a0 += h[(size_t)s0 * H + c] * w0;
        a1 += h[(size_t)s1 * H + c] * w1;
        a2 += h[(size_t)s2 * H + c] * w2;
        a3 += h[(size_t)s3 * H + c] * w3;
        a4 += h[(size_t)s4 * H + c] * w4;
        a5 += h[(size_t)s5 * H + c] * w5;
        a6 += h[(size_t)s6 * H + c] * w6;
        a7 += h[(size_t)s7 * H + c] * w7;
    }
    for (; j + 4 <= j1; j += 4) {
        int s0 = csr_src[j + 0], s1 = csr_src[j + 1], s2 = csr_src[j + 2], s3 = csr_src[j + 3];
        float w0 = csr_w[j + 0], w1 = csr_w[j + 1], w2 = csr_w[j + 2], w3 = csr_w[j + 3];
        a0 += h[(size_t)s0 * H + c] * w0;
        a1 += h[(size_t)s1 * H + c] * w1;
        a2 += h[(size_t)s2 * H + c] * w2;
        a3 += h[(size_t)s3 * H + c] * w3;
    }
    for (; j < j1; ++j) a0 += h[(size_t)csr_src[j] * H + c] * csr_w[j];
    out[(size_t)d * H + c] = ((a0 + a1) + (a2 + a3)) + ((a4 + a5) + (a6 + a7));
}

// ---------------- batchnorm stats ----------------
__global__ void bn_stats(const float* __restrict__ x, float* __restrict__ sum,
                         float* __restrict__ sumsq, int n) {
    int c = threadIdx.x & 63;
    int rg = threadIdx.x >> 6;  // 0..3
    int base = blockIdx.x * 256;
    float s = 0.f, sq = 0.f;
    for (int r = rg; r < 256; r += 4) {
        int row = base + r;
        if (row < n) {
            float v = x[(size_t)row * H + c];
            s += v;
            sq += v * v;
        }
    }
    __shared__ float ls[256], lq[256];
    ls[threadIdx.x] = s;
    lq[threadIdx.x] = sq;
    __syncthreads();
    if (rg == 0) {
        s = ls[c] + ls[c + 64] + ls[c + 128] + ls[c + 192];
        sq = lq[c] + lq[c + 64] + lq[c + 128] + lq[c + 192];
        atomicAdd(&sum[c], s);
        atomicAdd(&sumsq[c], sq);
    }
}

__global__ void bn_finalize(float* __restrict__ stats, const float* __restrict__ g,
                            const float* __restrict__ be, int n) {
    int c = threadIdx.x;
    if (c >= H) return;
    float mean = stats[c] / (float)n;
    float var = stats[64 + c] / (float)n - mean * mean;
    float sc = g[c] * rsqrtf(var + BN_EPS);
    stats[128 + c] = sc;
    stats[192 + c] = be[c] - mean * sc;
}

// ---------------- global mean pool (fuses last BN+ReLU); batch sorted ----------------
#define PROWS 128
__global__ void pool_seg(const float* __restrict__ h, const float* __restrict__ stats,
                         const int* __restrict__ batch, float* __restrict__ pool,
                         float* __restrict__ cnt, int n) {
    int wave = blockIdx.x * 4 + (threadIdx.x >> 6);
    int c = threadIdx.x & 63;
    int r0 = wave * PROWS;
    if (r0 >= n) return;
    int r1 = min(r0 + PROWS, n);
    float sc = stats[128 + c], sh = stats[192 + c];
    int cur = batch[r0];
    float acc = 0.f;
    int nlocal = 0;
    for (int r = r0; r < r1; ++r) {
        int g = batch[r];
        if (g != cur) {
            atomicAdd(&pool[cur * H + c], acc);
            if (c == 0) atomicAdd(&cnt[cur], (float)nlocal);
            cur = g;
            acc = 0.f;
            nlocal = 0;
        }
        acc += fmaxf(h[(size_t)r * H + c] * sc + sh, 0.f);
        ++nlocal;
    }
    atomicAdd(&pool[cur * H + c], acc);
    if (c == 0) atomicAdd(&cnt[cur], (float)nlocal);
}

// ---------------- final MLP: one thread per graph ----------------
__global__ void final_mlp(const float* __restrict__ pool, const float* __restrict__ cnt,
                          const float* __restrict__ l1w, const float* __restrict__ l1b,
                          const float* __restrict__ l2w, const float* __restrict__ l2b,
                          float* __restrict__ out) {
    int g = threadIdx.x;
    if (g >= NG) return;
    float c = fmaxf(cnt[g], 1.0f);
    float inv = 1.0f / c;
    float p[H];
#pragma unroll
    for (int k = 0; k < H; ++k) p[k] = pool[g * H + k] * inv;
    float acc = l2b[0];
    for (int j = 0; j < 32; ++j) {
        float s = l1b[j];
#pragma unroll
        for (int k = 0; k < H; ++k) s += p[k] * l1w[j * H + k];
        acc += fmaxf(s, 0.0f) * l2w[j];
    }
    out[g] = acc;
}

extern "C" void kernel_launch(void* const* d_in, const int* in_sizes, int n_in,
                              void* d_out, int out_size, void* d_ws, size_t ws_size,
                              hipStream_t stream) {
    const float* x = (const float*)d_in[0];
    const int* ei = (const int*)d_in[1];
    const int* batch = (const int*)d_in[2];
    const float* W[3] = {(const float*)d_in[3], (const float*)d_in[7], (const float*)d_in[11]};
    const float* b[3] = {(const float*)d_in[4], (const float*)d_in[8], (const float*)d_in[12]};
    const float* g[3] = {(const float*)d_in[5], (const float*)d_in[9], (const float*)d_in[13]};
    const float* be[3] = {(const float*)d_in[6], (const float*)d_in[10], (const float*)d_in[14]};
    const float* l1w = (const float*)d_in[15];
    const float* l1b = (const float*)d_in[16];
    const float* l2w = (const float*)d_in[17];
    const float* l2b = (const float*)d_in[18];
    float* out = (float*)d_out;

    const int* src = ei;
    const int* dst = ei + NE;

    // ---- workspace layout (4-byte units) ----
    char* wsb = (char*)d_ws;
    size_t off = 0;
    auto alloc = [&](size_t elems) {
        void* p = wsb + off;
        off += elems * 4;
        return p;
    };
    float* dinv = (float*)alloc(50048);
    float* bufA = (float*)alloc((size_t)NN * H);
    float* bufB = (float*)alloc((size_t)NN * H);
    float* st[3] = {(float*)alloc(256), (float*)alloc(256), (float*)alloc(256)};
    float* pool = (float*)alloc(NG * H);
    float* cnt = (float*)alloc(64);
    float* Wt[3] = {(float*)alloc(FIN * 64), (float*)alloc(H * 64), (float*)alloc(H * 64)};
    int* deg = (int*)alloc(50048);
    int* row_start = (int*)alloc(50112);  // NN+1
    int* aux = (int*)alloc(256);
    int* cursor = (int*)alloc(50048);
    int* csr_src = (int*)alloc(NE);
    float* csr_w = (float*)alloc(NE);

    // ---- build dinv + CSR (by dst) + transposed weights ----
    hipMemsetAsync(deg, 0, NN * sizeof(int), stream);
    deg_count<<<(NE + 255) / 256, 256, 0, stream>>>(dst, deg, NE);
    deg_to_dinv<<<(NN + 255) / 256, 256, 0, stream>>>(deg, dinv, st[0], st[1], st[2], pool, NN);
    scan_block<<<NB_SCAN, 256, 0, stream>>>(deg, row_start, aux, NN);
    scan_aux<<<1, 256, 0, stream>>>(aux, NB_SCAN);
    scan_fixup<<<NB_SCAN, 256, 0, stream>>>(row_start, aux, cursor, NN, NE);
    csr_scatter<<<(NE + 255) / 256, 256, 0, stream>>>(src, dst, dinv, cursor, csr_src, csr_w, NE);
    transpose_w<FIN><<<(FIN * 64 + 255) / 256, 256, 0, stream>>>(W[0], Wt[0]);
    transpose_w<H><<<(H * 64 + 255) / 256, 256, 0, stream>>>(W[1], Wt[1]);
    transpose_w<H><<<(H * 64 + 255) / 256, 256, 0, stream>>>(W[2], Wt[2]);

    const int grid_mm = (NN + 31) / 32;   // 1563
    const int grid_rows = (NN + 3) / 4;   // 12500
    const int grid_bn4 = (NN * 16 + 255) / 256;  // 3125

    // ---- 3 GCN layers ----
    for (int L = 0; L < 3; ++L) {
        if (L == 0) {
            matmul_rows8<FIN><<<grid_mm, 256, 0, stream>>>(x, Wt[0], bufA, NN);
        } else {
            bn_apply4<<<grid_bn4, 256, 0, stream>>>(bufB, st[L - 1], NN * 16);
            matmul_rows8<H><<<grid_mm, 256, 0, stream>>>(bufB, Wt[L], bufA, NN);
        }
        gcn_gather<<<grid_rows, 256, 0, stream>>>(bufA, row_start, csr_src, csr_w, dinv, b[L],
                                                  bufB, NN);
        bn_stats<<<196, 256, 0, stream>>>(bufB, st[L], st[L] + 64, NN);
        bn_finalize<<<1, 64, 0, stream>>>(st[L], g[L], be[L], NN);
    }

    // ---- global mean pool (fused BN of layer 2) + MLP head ----
    pool_seg<<<(((NN + PROWS - 1) / PROWS) + 3) / 4, 256, 0, stream>>>(bufB, st[2], batch, pool,
                                                                      cnt, NN);
    final_mlp<<<1, 64, 0, stream>>>(pool, cnt, l1w, l1b, l2w, l2b, out);
}

// Round 8
// 468.164 us; speedup vs baseline: 2.9290x; 1.2123x over previous
//
#include <hip/hip_runtime.h>

#define NN 50000
#define NE 800000
#define FIN 128
#define H 64
#define NG 64
#define BN_EPS 1e-5f
#define NB_SCAN 196  // ceil(NN/256)

// ---------------- degree histogram (int) ----------------
__global__ void deg_count(const int* __restrict__ dst, int* __restrict__ deg, int E) {
    int e = blockIdx.x * blockDim.x + threadIdx.x;
    if (e < E) atomicAdd(&deg[dst[e]], 1);
}

// also zeroes the BN-stat accumulators and pool/cnt (folds 4 memset launches)
__global__ void deg_to_dinv(const int* __restrict__ deg, float* __restrict__ dinv,
                            float* __restrict__ z0, float* __restrict__ z1,
                            float* __restrict__ z2, float* __restrict__ poolcnt, int n) {
    int i = blockIdx.x * blockDim.x + threadIdx.x;
    if (i < n) dinv[i] = rsqrtf((float)deg[i] + 1.0f);
    if (i < 128) { z0[i] = 0.f; z1[i] = 0.f; z2[i] = 0.f; }
    if (i < NG * H + NG) poolcnt[i] = 0.f;
}

// ---------------- prefix sum (exclusive) over deg -> row_start ----------------
__global__ void scan_block(const int* __restrict__ deg, int* __restrict__ row_start,
                           int* __restrict__ aux, int n) {
    __shared__ int s[256];
    int i = blockIdx.x * 256 + threadIdx.x;
    int v = (i < n) ? deg[i] : 0;
    s[threadIdx.x] = v;
    __syncthreads();
    for (int off = 1; off < 256; off <<= 1) {
        int t = (threadIdx.x >= off) ? s[threadIdx.x - off] : 0;
        __syncthreads();
        s[threadIdx.x] += t;
        __syncthreads();
    }
    if (i < n) row_start[i] = s[threadIdx.x] - v;  // exclusive
    if (threadIdx.x == 255) aux[blockIdx.x] = s[255];
}

__global__ void scan_aux(int* __restrict__ aux, int nb) {
    __shared__ int s[256];
    int v = (threadIdx.x < nb) ? aux[threadIdx.x] : 0;
    s[threadIdx.x] = v;
    __syncthreads();
    for (int off = 1; off < 256; off <<= 1) {
        int t = (threadIdx.x >= off) ? s[threadIdx.x - off] : 0;
        __syncthreads();
        s[threadIdx.x] += t;
        __syncthreads();
    }
    if (threadIdx.x < nb) aux[threadIdx.x] = s[threadIdx.x] - v;  // exclusive
}

__global__ void scan_fixup(int* __restrict__ row_start, const int* __restrict__ aux,
                           int* __restrict__ cursor, int n, int E) {
    int i = blockIdx.x * 256 + threadIdx.x;
    if (i < n) {
        int rs = row_start[i] + aux[i >> 8];
        row_start[i] = rs;
        cursor[i] = rs;
    }
    if (i == 0) row_start[n] = E;
}

// ---------------- scatter edges into CSR (by dst), precompute weights ----------------
__global__ void csr_scatter(const int* __restrict__ src, const int* __restrict__ dst,
                            const float* __restrict__ dinv, int* __restrict__ cursor,
                            int* __restrict__ csr_src, float* __restrict__ csr_w, int E) {
    int e = blockIdx.x * blockDim.x + threadIdx.x;
    if (e >= E) return;
    int s = src[e], d = dst[e];
    int j = atomicAdd(&cursor[d], 1);
    csr_src[j] = s;
    csr_w[j] = dinv[s] * dinv[d];
}

// ---------------- transpose all 3 W once: Wt[k*64 + o] = W[o*K + k] ----------------
__global__ void transpose_all(const float* __restrict__ W0, const float* __restrict__ W1,
                              const float* __restrict__ W2, float* __restrict__ Wt0,
                              float* __restrict__ Wt1, float* __restrict__ Wt2) {
    int i = blockIdx.x * 256 + threadIdx.x;
    if (i < FIN * 64) {
        int k = i >> 6, o = i & 63;
        Wt0[i] = W0[o * FIN + k];
    }
    if (i < H * 64) {
        int k = i >> 6, o = i & 63;
        Wt1[i] = W1[o * H + k];
        Wt2[i] = W2[o * H + k];
    }
}

// ---------------- tiled matmul: out = relu_bn(x) @ W^T ----------------
// 64x64 tile, 256 threads, 4x4 thread tile. Lessons encoded:
//  - no indexed private arrays (R3/R4 scratch spill: FETCH 493-867 MB)
//  - #pragma unroll 2 only (full unroll -> compiler pipelines 128+ regs -> spill)
//  - BN+ReLU applied at STAGE time only (R6: inner-loop fusion -> VGPR 188)
//  - scattered rows per thread (q,q+16,q+32,q+48): X b128 reads hit disjoint
//    bank spans (consecutive-quad would be structural 8-way: 4*68 = 16 mod 32)
//  - Xs row stride 68: fill writes 2-way (free), compute reads conflict-free
//  - Ws linear copy of pre-transposed Wt; compute read co in {0,4..60} -> 2-way
template <int K>
__global__ __launch_bounds__(256, 4) void matmul_tile(const float* __restrict__ x,
                                                      const float* __restrict__ Wtg,
                                                      const float* __restrict__ stats,
                                                      float* __restrict__ out, int n) {
    __shared__ float Xs[64 * 68];
    __shared__ float Ws[64 * 64];
    const int base = blockIdx.x * 64;
    const int q = threadIdx.x >> 4;         // 0..15
    const int co = (threadIdx.x & 15) * 4;  // 0..60

    float4 a0 = make_float4(0.f, 0.f, 0.f, 0.f);
    float4 a1 = a0, a2 = a0, a3 = a0;

    for (int kc = 0; kc < K; kc += 64) {
        if (kc) __syncthreads();
        // stage W chunk (pure linear copy)
        for (int i = threadIdx.x; i < 64 * 64; i += 256) Ws[i] = Wtg[kc * 64 + i];
        // stage X chunk, coalesced; optional BN+ReLU of previous layer
        {
            const int kq = (threadIdx.x & 15) * 4;
            float4 sc = make_float4(1.f, 1.f, 1.f, 1.f);
            float4 sh = make_float4(0.f, 0.f, 0.f, 0.f);
            if (stats) {
                sc = *(const float4*)&stats[128 + kc + kq];
                sh = *(const float4*)&stats[192 + kc + kq];
            }
            for (int j = 0; j < 4; ++j) {
                int r = (threadIdx.x >> 4) + j * 16;
                int row = base + r;
                float4 v = make_float4(0.f, 0.f, 0.f, 0.f);
                if (row < n) v = *(const float4*)&x[(size_t)row * K + kc + kq];
                if (stats) {
                    v.x = fmaxf(v.x * sc.x + sh.x, 0.f);
                    v.y = fmaxf(v.y * sc.y + sh.y, 0.f);
                    v.z = fmaxf(v.z * sc.z + sh.z, 0.f);
                    v.w = fmaxf(v.w * sc.w + sh.w, 0.f);
                }
                *(float4*)&Xs[r * 68 + kq] = v;
            }
        }
        __syncthreads();

#pragma unroll 2
        for (int k = 0; k < 64; k += 4) {
            float4 x0 = *(const float4*)&Xs[(q + 0) * 68 + k];
            float4 x1 = *(const float4*)&Xs[(q + 16) * 68 + k];
            float4 x2 = *(const float4*)&Xs[(q + 32) * 68 + k];
            float4 x3 = *(const float4*)&Xs[(q + 48) * 68 + k];
            float4 w0 = *(const float4*)&Ws[(k + 0) * 64 + co];
            float4 w1 = *(const float4*)&Ws[(k + 1) * 64 + co];
            float4 w2 = *(const float4*)&Ws[(k + 2) * 64 + co];
            float4 w3 = *(const float4*)&Ws[(k + 3) * 64 + co];

            a0.x += x0.x * w0.x + x0.y * w1.x + x0.z * w2.x + x0.w * w3.x;
            a0.y += x0.x * w0.y + x0.y * w1.y + x0.z * w2.y + x0.w * w3.y;
            a0.z += x0.x * w0.z + x0.y * w1.z + x0.z * w2.z + x0.w * w3.z;
            a0.w += x0.x * w0.w + x0.y * w1.w + x0.z * w2.w + x0.w * w3.w;

            a1.x += x1.x * w0.x + x1.y * w1.x + x1.z * w2.x + x1.w * w3.x;
            a1.y += x1.x * w0.y + x1.y * w1.y + x1.z * w2.y + x1.w * w3.y;
            a1.z += x1.x * w0.z + x1.y * w1.z + x1.z * w2.z + x1.w * w3.z;
            a1.w += x1.x * w0.w + x1.y * w1.w + x1.z * w2.w + x1.w * w3.w;

            a2.x += x2.x * w0.x + x2.y * w1.x + x2.z * w2.x + x2.w * w3.x;
            a2.y += x2.x * w0.y + x2.y * w1.y + x2.z * w2.y + x2.w * w3.y;
            a2.z += x2.x * w0.z + x2.y * w1.z + x2.z * w2.z + x2.w * w3.z;
            a2.w += x2.x * w0.w + x2.y * w1.w + x2.z * w2.w + x2.w * w3.w;

            a3.x += x3.x * w0.x + x3.y * w1.x + x3.z * w2.x + x3.w * w3.x;
            a3.y += x3.x * w0.y + x3.y * w1.y + x3.z * w2.y + x3.w * w3.y;
            a3.z += x3.x * w0.z + x3.y * w1.z + x3.z * w2.z + x3.w * w3.z;
            a3.w += x3.x * w0.w + x3.y * w1.w + x3.z * w2.w + x3.w * w3.w;
        }
    }

    int r0 = base + q;
    if (r0 < n) *(float4*)&out[(size_t)r0 * H + co] = a0;
    if (r0 + 16 < n) *(float4*)&out[(size_t)(r0 + 16) * H + co] = a1;
    if (r0 + 32 < n) *(float4*)&out[(size_t)(r0 + 32) * H + co] = a2;
    if (r0 + 48 < n) *(float4*)&out[(size_t)(r0 + 48) * H + co] = a3;
}

// ---------------- fused GCN aggregation: gather over CSR + self-loop + bias -------------
// 8 independent gather chains in flight per wave (R5 1-chain was latency-bound).
__global__ void gcn_gather(const float* __restrict__ h, const int* __restrict__ row_start,
                           const int* __restrict__ csr_src, const float* __restrict__ csr_w,
                           const float* __restrict__ dinv, const float* __restrict__ bias,
                           float* __restrict__ out, int n) {
    int d = blockIdx.x * 4 + (threadIdx.x >> 6);
    int c = threadIdx.x & 63;
    if (d >= n) return;
    float di = dinv[d];
    float a0 = h[(size_t)d * H + c] * di * di + bias[c];
    float a1 = 0.f, a2 = 0.f, a3 = 0.f, a4 = 0.f, a5 = 0.f, a6 = 0.f, a7 = 0.f;
    int j0 = row_start[d], j1 = row_start[d + 1];
    int j = j0;
    for (; j + 8 <= j1; j += 8) {
        int s0 = csr_src[j + 0], s1 = csr_src[j + 1], s2 = csr_src[j + 2], s3 = csr_src[j + 3];
        int s4 = csr_src[j + 4], s5 = csr_src[j + 5], s6 = csr_src[j + 6], s7 = csr_src[j + 7];
        float w0 = csr_w[j + 0], w1 = csr_w[j + 1], w2 = csr_w[j + 2], w3 = csr_w[j + 3];
        float w4 = csr_w[j + 4], w5 = csr_w[j + 5], w6 = csr_w[j + 6], w7 = csr_w[j + 7];
        a0 += h[(size_t)s0 * H + c] * w0;
        a1 += h[(size_t)s1 * H + c] * w1;
        a2 += h[(size_t)s2 * H + c] * w2;
        a3 += h[(size_t)s3 * H + c] * w3;
        a4 += h[(size_t)s4 * H + c] * w4;
        a5 += h[(size_t)s5 * H + c] * w5;
        a6 += h[(size_t)s6 * H + c] * w6;
        a7 += h[(size_t)s7 * H + c] * w7;
    }
    for (; j + 4 <= j1; j += 4) {
        int s0 = csr_src[j + 0], s1 = csr_src[j + 1], s2 = csr_src[j + 2], s3 = csr_src[j + 3];
        float w0 = csr_w[j + 0], w1 = csr_w[j + 1], w2 = csr_w[j + 2], w3 = csr_w[j + 3];
        a0 += h[(size_t)s0 * H + c] * w0;
        a1 += h[(size_t)s1 * H + c] * w1;
        a2 += h[(size_t)s2 * H + c] * w2;
        a3 += h[(size_t)s3 * H + c] * w3;
    }
    for (; j < j1; ++j) a0 += h[(size_t)csr_src[j] * H + c] * csr_w[j];
    out[(size_t)d * H + c] = ((a0 + a1) + (a2 + a3)) + ((a4 + a5) + (a6 + a7));
}

// ---------------- batchnorm stats ----------------
__global__ void bn_stats(const float* __restrict__ x, float* __restrict__ sum,
                         float* __restrict__ sumsq, int n) {
    int c = threadIdx.x & 63;
    int rg = threadIdx.x >> 6;  // 0..3
    int base = blockIdx.x * 256;
    float s = 0.f, sq = 0.f;
    for (int r = rg; r < 256; r += 4) {
        int row = base + r;
        if (row < n) {
            float v = x[(size_t)row * H + c];
            s += v;
            sq += v * v;
        }
    }
    __shared__ float ls[256], lq[256];
    ls[threadIdx.x] = s;
    lq[threadIdx.x] = sq;
    __syncthreads();
    if (rg == 0) {
        s = ls[c] + ls[c + 64] + ls[c + 128] + ls[c + 192];
        sq = lq[c] + lq[c + 64] + lq[c + 128] + lq[c + 192];
        atomicAdd(&sum[c], s);
        atomicAdd(&sumsq[c], sq);
    }
}

__global__ void bn_finalize(float* __restrict__ stats, const float* __restrict__ g,
                            const float* __restrict__ be, int n) {
    int c = threadIdx.x;
    if (c >= H) return;
    float mean = stats[c] / (float)n;
    float var = stats[64 + c] / (float)n - mean * mean;
    float sc = g[c] * rsqrtf(var + BN_EPS);
    stats[128 + c] = sc;
    stats[192 + c] = be[c] - mean * sc;
}

// ---------------- global mean pool (fuses last BN+ReLU); batch sorted ----------------
#define PROWS 128
__global__ void pool_seg(const float* __restrict__ h, const float* __restrict__ stats,
                         const int* __restrict__ batch, float* __restrict__ pool,
                         float* __restrict__ cnt, int n) {
    int wave = blockIdx.x * 4 + (threadIdx.x >> 6);
    int c = threadIdx.x & 63;
    int r0 = wave * PROWS;
    if (r0 >= n) return;
    int r1 = min(r0 + PROWS, n);
    float sc = stats[128 + c], sh = stats[192 + c];
    int cur = batch[r0];
    float acc = 0.f;
    int nlocal = 0;
    for (int r = r0; r < r1; ++r) {
        int g = batch[r];
        if (g != cur) {
            atomicAdd(&pool[cur * H + c], acc);
            if (c == 0) atomicAdd(&cnt[cur], (float)nlocal);
            cur = g;
            acc = 0.f;
            nlocal = 0;
        }
        acc += fmaxf(h[(size_t)r * H + c] * sc + sh, 0.f);
        ++nlocal;
    }
    atomicAdd(&pool[cur * H + c], acc);
    if (c == 0) atomicAdd(&cnt[cur], (float)nlocal);
}

// ---------------- final MLP: one thread per graph ----------------
__global__ void final_mlp(const float* __restrict__ pool, const float* __restrict__ cnt,
                          const float* __restrict__ l1w, const float* __restrict__ l1b,
                          const float* __restrict__ l2w, const float* __restrict__ l2b,
                          float* __restrict__ out) {
    int g = threadIdx.x;
    if (g >= NG) return;
    float c = fmaxf(cnt[g], 1.0f);
    float inv = 1.0f / c;
    float p[H];
#pragma unroll
    for (int k = 0; k < H; ++k) p[k] = pool[g * H + k] * inv;
    float acc = l2b[0];
    for (int j = 0; j < 32; ++j) {
        float s = l1b[j];
#pragma unroll
        for (int k = 0; k < H; ++k) s += p[k] * l1w[j * H + k];
        acc += fmaxf(s, 0.0f) * l2w[j];
    }
    out[g] = acc;
}

extern "C" void kernel_launch(void* const* d_in, const int* in_sizes, int n_in,
                              void* d_out, int out_size, void* d_ws, size_t ws_size,
                              hipStream_t stream) {
    const float* x = (const float*)d_in[0];
    const int* ei = (const int*)d_in[1];
    const int* batch = (const int*)d_in[2];
    const float* W[3] = {(const float*)d_in[3], (const float*)d_in[7], (const float*)d_in[11]};
    const float* b[3] = {(const float*)d_in[4], (const float*)d_in[8], (const float*)d_in[12]};
    const float* g[3] = {(const float*)d_in[5], (const float*)d_in[9], (const float*)d_in[13]};
    const float* be[3] = {(const float*)d_in[6], (const float*)d_in[10], (const float*)d_in[14]};
    const float* l1w = (const float*)d_in[15];
    const float* l1b = (const float*)d_in[16];
    const float* l2w = (const float*)d_in[17];
    const float* l2b = (const float*)d_in[18];
    float* out = (float*)d_out;

    const int* src = ei;
    const int* dst = ei + NE;

    // ---- workspace layout (4-byte units) ----
    char* wsb = (char*)d_ws;
    size_t off = 0;
    auto alloc = [&](size_t elems) {
        void* p = wsb + off;
        off += elems * 4;
        return p;
    };
    float* dinv = (float*)alloc(50048);
    float* bufA = (float*)alloc((size_t)NN * H);
    float* bufB = (float*)alloc((size_t)NN * H);
    float* st[3] = {(float*)alloc(256), (float*)alloc(256), (float*)alloc(256)};
    float* pool = (float*)alloc(NG * H);
    float* cnt = (float*)alloc(64);
    float* Wt[3] = {(float*)alloc(FIN * 64), (float*)alloc(H * 64), (float*)alloc(H * 64)};
    int* deg = (int*)alloc(50048);
    int* row_start = (int*)alloc(50112);  // NN+1
    int* aux = (int*)alloc(256);
    int* cursor = (int*)alloc(50048);
    int* csr_src = (int*)alloc(NE);
    float* csr_w = (float*)alloc(NE);

    // ---- build dinv + CSR (by dst) + transposed weights ----
    hipMemsetAsync(deg, 0, NN * sizeof(int), stream);
    deg_count<<<(NE + 255) / 256, 256, 0, stream>>>(dst, deg, NE);
    deg_to_dinv<<<(NN + 255) / 256, 256, 0, stream>>>(deg, dinv, st[0], st[1], st[2], pool, NN);
    scan_block<<<NB_SCAN, 256, 0, stream>>>(deg, row_start, aux, NN);
    scan_aux<<<1, 256, 0, stream>>>(aux, NB_SCAN);
    scan_fixup<<<NB_SCAN, 256, 0, stream>>>(row_start, aux, cursor, NN, NE);
    csr_scatter<<<(NE + 255) / 256, 256, 0, stream>>>(src, dst, dinv, cursor, csr_src, csr_w, NE);
    transpose_all<<<(FIN * 64 + 255) / 256, 256, 0, stream>>>(W[0], W[1], W[2], Wt[0], Wt[1],
                                                              Wt[2]);

    const int grid_mm = (NN + 63) / 64;   // 782
    const int grid_rows = (NN + 3) / 4;   // 12500

    // ---- 3 GCN layers (BN+ReLU of layer L-1 fused into layer L's X staging) ----
    for (int L = 0; L < 3; ++L) {
        if (L == 0)
            matmul_tile<FIN><<<grid_mm, 256, 0, stream>>>(x, Wt[0], nullptr, bufA, NN);
        else
            matmul_tile<H><<<grid_mm, 256, 0, stream>>>(bufB, Wt[L], st[L - 1], bufA, NN);
        gcn_gather<<<grid_rows, 256, 0, stream>>>(bufA, row_start, csr_src, csr_w, dinv, b[L],
                                                  bufB, NN);
        bn_stats<<<196, 256, 0, stream>>>(bufB, st[L], st[L] + 64, NN);
        bn_finalize<<<1, 64, 0, stream>>>(st[L], g[L], be[L], NN);
    }

    // ---- global mean pool (fused BN of layer 2) + MLP head ----
    pool_seg<<<(((NN + PROWS - 1) / PROWS) + 3) / 4, 256, 0, stream>>>(bufB, st[2], batch, pool,
                                                                      cnt, NN);
    final_mlp<<<1, 64, 0, stream>>>(pool, cnt, l1w, l1b, l2w, l2b, out);
}